// Round 1
// baseline (1975.891 us; speedup 1.0000x reference)
//
#include <hip/hip_runtime.h>
#include <cstdint>
#include <cstddef>

// Problem constants
static constexpr int H = 128, W = 128, HW = 128 * 128;
static constexpr int C = 128;              // Cout
static constexpr int HP = 130;             // padded KV map dim
static constexpr int HPHP = 130 * 130;
static constexpr float BN_EPS = 1e-5f;

// ---------------------------------------------------------------------------
// rep kernel: out = lrelu( conv3x3(bn(x)) + bias + residual )
//   RES_MODE 0: residual = conv1x1(bn(x), Wadj) + badj   (CIN=64 -> 128)
//   RES_MODE 1: residual = bn(x) (identity, CIN=128)
// grid: (8 co-tiles of 16, y=128, n=2); block 256: x = tid&127, half = tid>>7
// each thread: 8 output channels.
// ---------------------------------------------------------------------------
template <int CIN, int RES_MODE>
__global__ __launch_bounds__(256, 2)
void rep_kernel(const float* __restrict__ in,          // (2,CIN,128,128)
                const float* __restrict__ gamma, const float* __restrict__ beta,
                const float* __restrict__ mean_, const float* __restrict__ var_,
                const float* __restrict__ Wc,          // (128,CIN,3,3)
                const float* __restrict__ bc,          // (128)
                const float* __restrict__ Wadj,        // (128,CIN) or null
                const float* __restrict__ badj,        // (128) or null
                float* __restrict__ out)               // (2,128,128,128)
{
    const int tid = threadIdx.x;
    const int x = tid & 127;
    // readfirstlane: make co_base wave-uniform -> weight loads become s_loads
    const int half = __builtin_amdgcn_readfirstlane(tid >> 7);
    const int co_base = blockIdx.x * 16 + half * 8;
    const int y = blockIdx.y;
    const int n = blockIdx.z;

    __shared__ float lds[16][3][132];

    float acc[8];
#pragma unroll
    for (int j = 0; j < 8; ++j) {
        acc[j] = bc[co_base + j];
        if (RES_MODE == 0) acc[j] += badj[co_base + j];
    }

    const float* in_n = in + (size_t)n * CIN * HW;

    for (int ct = 0; ct < CIN / 16; ++ct) {
        __syncthreads();
        for (int idx = tid; idx < 16 * 3 * 130; idx += 256) {
            int ci = idx / 390;
            int rem = idx - ci * 390;
            int r = rem / 130;
            int xx = rem - r * 130;
            int cig = ct * 16 + ci;
            int yy = y + r - 1;
            int xi = xx - 1;
            float v = 0.f;
            if ((unsigned)yy < 128u && (unsigned)xi < 128u) {
                float s = gamma[cig] * rsqrtf(var_[cig] + BN_EPS);
                float t = beta[cig] - mean_[cig] * s;
                v = in_n[(size_t)cig * HW + yy * 128 + xi] * s + t;
            }
            lds[ci][r][xx] = v;
        }
        __syncthreads();

#pragma unroll 2
        for (int ci = 0; ci < 16; ++ci) {
            const int cig = ct * 16 + ci;
            float t00 = lds[ci][0][x], t01 = lds[ci][0][x + 1], t02 = lds[ci][0][x + 2];
            float t10 = lds[ci][1][x], t11 = lds[ci][1][x + 1], t12 = lds[ci][1][x + 2];
            float t20 = lds[ci][2][x], t21 = lds[ci][2][x + 1], t22 = lds[ci][2][x + 2];
#pragma unroll
            for (int j = 0; j < 8; ++j) {
                const float* w = Wc + ((size_t)(co_base + j) * CIN + cig) * 9;
                float a = acc[j];
                a += t00 * w[0]; a += t01 * w[1]; a += t02 * w[2];
                a += t10 * w[3]; a += t11 * w[4]; a += t12 * w[5];
                a += t20 * w[6]; a += t21 * w[7]; a += t22 * w[8];
                if (RES_MODE == 0) a += t11 * Wadj[(size_t)(co_base + j) * CIN + cig];
                acc[j] = a;
            }
            if (RES_MODE == 1) {
                int j = cig - co_base;              // wave-uniform branch
                if ((unsigned)j < 8u) acc[j] += t11;
            }
        }
    }

    float* outp = out + ((size_t)n * C + co_base) * HW + y * 128 + x;
#pragma unroll
    for (int j = 0; j < 8; ++j) {
        float v = acc[j];
        v = v > 0.f ? v : 0.05f * v;
        outp[(size_t)j * HW] = v;
    }
}

// ---------------------------------------------------------------------------
// conv1x1 kernel (Q projection): out = W * in + b, (2,128,128,128)
// ---------------------------------------------------------------------------
__global__ __launch_bounds__(256, 2)
void conv1x1_kernel(const float* __restrict__ in,
                    const float* __restrict__ Wp,   // (128,128)
                    const float* __restrict__ bp,
                    float* __restrict__ out)
{
    const int tid = threadIdx.x;
    const int x = tid & 127;
    const int half = __builtin_amdgcn_readfirstlane(tid >> 7);
    const int co_base = blockIdx.x * 16 + half * 8;
    const int y = blockIdx.y;
    const int n = blockIdx.z;

    __shared__ float lds[16][128];
    float acc[8];
#pragma unroll
    for (int j = 0; j < 8; ++j) acc[j] = bp[co_base + j];

    const float* in_n = in + (size_t)n * C * HW + y * 128;
    for (int ct = 0; ct < 8; ++ct) {
        __syncthreads();
        for (int idx = tid; idx < 16 * 128; idx += 256) {
            int ci = idx >> 7, xx = idx & 127;
            lds[ci][xx] = in_n[(size_t)(ct * 16 + ci) * HW + xx];
        }
        __syncthreads();
#pragma unroll
        for (int ci = 0; ci < 16; ++ci) {
            float v = lds[ci][x];
            int cig = ct * 16 + ci;
#pragma unroll
            for (int j = 0; j < 8; ++j)
                acc[j] += v * Wp[(size_t)(co_base + j) * C + cig];
        }
    }
    float* outp = out + ((size_t)n * C + co_base) * HW + y * 128 + x;
#pragma unroll
    for (int j = 0; j < 8; ++j) outp[(size_t)j * HW] = acc[j];
}

// ---------------------------------------------------------------------------
// KV projection with pad-before-conv: out (2,128,130,130); border = bias.
// grid: (8, 130, 2)
// ---------------------------------------------------------------------------
__global__ __launch_bounds__(256, 2)
void kvproj_kernel(const float* __restrict__ in,   // (2,128,128,128)
                   const float* __restrict__ Wp,   // (128,128)
                   const float* __restrict__ bp,
                   float* __restrict__ out)        // (2,128,130,130)
{
    const int tid = threadIdx.x;
    const int x = tid & 127;
    const int half = __builtin_amdgcn_readfirstlane(tid >> 7);
    const int co_base = blockIdx.x * 16 + half * 8;
    const int yy = blockIdx.y;   // 0..129
    const int n = blockIdx.z;

    float* out_n = out + (size_t)n * C * HPHP;

    if (yy == 0 || yy == 129) {
        for (int xx = x; xx < 130; xx += 128) {
#pragma unroll
            for (int j = 0; j < 8; ++j)
                out_n[(size_t)(co_base + j) * HPHP + yy * HP + xx] = bp[co_base + j];
        }
        return;
    }

    __shared__ float lds[16][128];
    float acc[8];
#pragma unroll
    for (int j = 0; j < 8; ++j) acc[j] = bp[co_base + j];

    const float* in_n = in + (size_t)n * C * HW + (yy - 1) * 128;
    for (int ct = 0; ct < 8; ++ct) {
        __syncthreads();
        for (int idx = tid; idx < 16 * 128; idx += 256) {
            int ci = idx >> 7, xx = idx & 127;
            lds[ci][xx] = in_n[(size_t)(ct * 16 + ci) * HW + xx];
        }
        __syncthreads();
#pragma unroll
        for (int ci = 0; ci < 16; ++ci) {
            float v = lds[ci][x];
            int cig = ct * 16 + ci;
#pragma unroll
            for (int j = 0; j < 8; ++j)
                acc[j] += v * Wp[(size_t)(co_base + j) * C + cig];
        }
    }
#pragma unroll
    for (int j = 0; j < 8; ++j)
        out_n[(size_t)(co_base + j) * HPHP + yy * HP + (x + 1)] = acc[j];
    if (x < 2) {
        int xx = x * 129;   // 0 or 129
#pragma unroll
        for (int j = 0; j < 8; ++j)
            out_n[(size_t)(co_base + j) * HPHP + yy * HP + xx] = bp[co_base + j];
    }
}

// ---------------------------------------------------------------------------
// attention: per pixel, per head: 9 logits over 3x3 window of kvp, softmax,
// weighted sum of kv; accumulate 0.5x into pass. grid (128 y, 8 = n*4+h)
// ---------------------------------------------------------------------------
__global__ __launch_bounds__(128, 4)
void attn_kernel(const float* __restrict__ q,     // (2,128,128,128)
                 const float* __restrict__ kvp,   // (2,128,130,130)
                 float* __restrict__ pass,        // (2,128,128,128)
                 int accumulate)
{
    const int x = threadIdx.x;        // 0..127
    const int y = blockIdx.x;         // 0..127
    const int h = blockIdx.y & 3;
    const int n = blockIdx.y >> 2;
    const float scale = 0.17677669529663687f;   // 32^-0.5

    const float* qp = q + (((size_t)n * C + h * 32) * H + y) * W + x;
    const float* kp = kvp + ((size_t)n * C + h * 32) * HPHP + y * HP + x;

    float logit[9];
#pragma unroll
    for (int t = 0; t < 9; ++t) logit[t] = 0.f;

    for (int d = 0; d < 32; ++d) {
        float qv = qp[(size_t)d * HW] * scale;
        const float* kd = kp + (size_t)d * HPHP;
#pragma unroll
        for (int ty = 0; ty < 3; ++ty)
#pragma unroll
            for (int tx = 0; tx < 3; ++tx)
                logit[ty * 3 + tx] += qv * kd[ty * HP + tx];
    }

    float m = logit[0];
#pragma unroll
    for (int t = 1; t < 9; ++t) m = fmaxf(m, logit[t]);
    float e[9], s = 0.f;
#pragma unroll
    for (int t = 0; t < 9; ++t) { e[t] = __expf(logit[t] - m); s += e[t]; }
    const float inv = 0.5f / s;

    float* pp = pass + (((size_t)n * C + h * 32) * H + y) * W + x;
    for (int d = 0; d < 32; ++d) {
        const float* kd = kp + (size_t)d * HPHP;
        float o = 0.f;
#pragma unroll
        for (int ty = 0; ty < 3; ++ty)
#pragma unroll
            for (int tx = 0; tx < 3; ++tx)
                o += e[ty * 3 + tx] * kd[ty * HP + tx];
        o *= inv;
        if (accumulate) pp[(size_t)d * HW] += o;
        else            pp[(size_t)d * HW] = o;
    }
}

// ---------------------------------------------------------------------------
// pooling conv 3x3 stride 2 pad 1: (2,128,128,128) -> (2,128,64,64)
// grid: (8 co-tiles of 16, yo=64, n=2); block 256: xo = tid&63, grp = tid>>6
// ---------------------------------------------------------------------------
__global__ __launch_bounds__(256, 2)
void pool_kernel(const float* __restrict__ in,
                 const float* __restrict__ Wp,   // (128,128,3,3)
                 const float* __restrict__ bp,
                 float* __restrict__ out)        // (2,128,64,64)
{
    const int tid = threadIdx.x;
    const int xo = tid & 63;
    const int grp = __builtin_amdgcn_readfirstlane(tid >> 6);  // 0..3
    const int co_base = blockIdx.x * 16 + grp * 4;
    const int yo = blockIdx.y;
    const int n = blockIdx.z;

    __shared__ float lds[16][3][132];
    float acc[4];
#pragma unroll
    for (int j = 0; j < 4; ++j) acc[j] = bp[co_base + j];

    const float* in_n = in + (size_t)n * C * HW;
    for (int ct = 0; ct < 8; ++ct) {
        __syncthreads();
        for (int idx = tid; idx < 16 * 3 * 129; idx += 256) {
            int ci = idx / 387;
            int rem = idx - ci * 387;
            int r = rem / 129;
            int xx = rem - r * 129;
            int yi = 2 * yo + r - 1;
            int xi = xx - 1;
            float v = 0.f;
            if ((unsigned)yi < 128u && (unsigned)xi < 128u)
                v = in_n[(size_t)(ct * 16 + ci) * HW + yi * 128 + xi];
            lds[ci][r][xx] = v;
        }
        __syncthreads();

#pragma unroll 2
        for (int ci = 0; ci < 16; ++ci) {
            const int cig = ct * 16 + ci;
            float t0 = lds[ci][0][2 * xo], t1 = lds[ci][0][2 * xo + 1], t2 = lds[ci][0][2 * xo + 2];
            float t3 = lds[ci][1][2 * xo], t4 = lds[ci][1][2 * xo + 1], t5 = lds[ci][1][2 * xo + 2];
            float t6 = lds[ci][2][2 * xo], t7 = lds[ci][2][2 * xo + 1], t8 = lds[ci][2][2 * xo + 2];
#pragma unroll
            for (int j = 0; j < 4; ++j) {
                const float* w = Wp + ((size_t)(co_base + j) * C + cig) * 9;
                float a = acc[j];
                a += t0 * w[0]; a += t1 * w[1]; a += t2 * w[2];
                a += t3 * w[3]; a += t4 * w[4]; a += t5 * w[5];
                a += t6 * w[6]; a += t7 * w[7]; a += t8 * w[8];
                acc[j] = a;
            }
        }
    }

    float* outp = out + ((size_t)n * C + co_base) * 4096 + yo * 64 + xo;
#pragma unroll
    for (int j = 0; j < 4; ++j) outp[(size_t)j * 4096] = acc[j];
}

// ---------------------------------------------------------------------------
extern "C" void kernel_launch(void* const* d_in, const int* in_sizes, int n_in,
                              void* d_out, int out_size, void* d_ws, size_t ws_size,
                              hipStream_t stream)
{
    const float* x0 = (const float*)d_in[0];
    const float* x1 = (const float*)d_in[1];
    const float* x2 = (const float*)d_in[2];
    const float* gamma0 = (const float*)d_in[3];
    const float* beta0  = (const float*)d_in[4];
    const float* mean0  = (const float*)d_in[5];
    const float* var0   = (const float*)d_in[6];
    const float* gamma1 = (const float*)d_in[7];
    const float* beta1  = (const float*)d_in[8];
    const float* mean1  = (const float*)d_in[9];
    const float* var1   = (const float*)d_in[10];
    const float* W_adj  = (const float*)d_in[11];
    const float* b_adj  = (const float*)d_in[12];
    const float* W_conv0 = (const float*)d_in[13];
    const float* b_conv0 = (const float*)d_in[14];
    const float* W_conv1 = (const float*)d_in[15];
    const float* b_conv1 = (const float*)d_in[16];
    const float* Wq  = (const float*)d_in[17];
    const float* bq  = (const float*)d_in[18];
    const float* Wkv = (const float*)d_in[19];
    const float* bkv = (const float*)d_in[20];
    const float* W_pool = (const float*)d_in[21];
    const float* b_pool = (const float*)d_in[22];

    float* out = (float*)d_out;
    float* out_n0 = out;                       // (2,128,64,64)
    float* out_n1 = out + 1048576;
    float* out_n2 = out + 2097152;
    float* pass   = out + 3145728;             // (2,128,128,128)

    const size_t SLOT = 4326400;               // floats; max(4194304, 2*128*130*130)
    float* S0 = (float*)d_ws;
    float* S1 = S0 + SLOT;
    float* S2 = S1 + SLOT;
    float* S3 = S2 + SLOT;

    dim3 gridRep(8, 128, 2), blk256(256);

    // rep0: x -> S0/S1/S2
    rep_kernel<64, 0><<<gridRep, blk256, 0, stream>>>(x0, gamma0, beta0, mean0, var0,
                                                      W_conv0, b_conv0, W_adj, b_adj, S0);
    rep_kernel<64, 0><<<gridRep, blk256, 0, stream>>>(x1, gamma0, beta0, mean0, var0,
                                                      W_conv0, b_conv0, W_adj, b_adj, S1);
    rep_kernel<64, 0><<<gridRep, blk256, 0, stream>>>(x2, gamma0, beta0, mean0, var0,
                                                      W_conv0, b_conv0, W_adj, b_adj, S2);

    // rep1: S0 -> S3 (n0f); S1 -> pass (n1f); S2 -> S0 (n2f)
    rep_kernel<128, 1><<<gridRep, blk256, 0, stream>>>(S0, gamma1, beta1, mean1, var1,
                                                       W_conv1, b_conv1, nullptr, nullptr, S3);
    rep_kernel<128, 1><<<gridRep, blk256, 0, stream>>>(S1, gamma1, beta1, mean1, var1,
                                                       W_conv1, b_conv1, nullptr, nullptr, pass);
    rep_kernel<128, 1><<<gridRep, blk256, 0, stream>>>(S2, gamma1, beta1, mean1, var1,
                                                       W_conv1, b_conv1, nullptr, nullptr, S0);

    // Q projection: pass (n1f) -> S1
    conv1x1_kernel<<<dim3(8, 128, 2), blk256, 0, stream>>>(pass, Wq, bq, S1);

    // branch 1: kv from n0f (S3)
    kvproj_kernel<<<dim3(8, 130, 2), blk256, 0, stream>>>(S3, Wkv, bkv, S2);
    attn_kernel<<<dim3(128, 8), dim3(128), 0, stream>>>(S1, S2, pass, 0);

    // branch 2: kv from n2f (S0)
    kvproj_kernel<<<dim3(8, 130, 2), blk256, 0, stream>>>(S0, Wkv, bkv, S2);
    attn_kernel<<<dim3(128, 8), dim3(128), 0, stream>>>(S1, S2, pass, 1);

    // pooling
    dim3 gridPool(8, 64, 2);
    pool_kernel<<<gridPool, blk256, 0, stream>>>(S3, W_pool, b_pool, out_n0);
    pool_kernel<<<gridPool, blk256, 0, stream>>>(pass, W_pool, b_pool, out_n1);
    pool_kernel<<<gridPool, blk256, 0, stream>>>(S0, W_pool, b_pool, out_n2);
}

// Round 2
// 516.452 us; speedup vs baseline: 3.8259x; 3.8259x over previous
//
#include <hip/hip_runtime.h>
#include <cstdint>
#include <cstddef>

// ---------------------------------------------------------------------------
// Types / helpers
// ---------------------------------------------------------------------------
typedef __bf16 bf16x8 __attribute__((ext_vector_type(8)));
typedef float f32x4 __attribute__((ext_vector_type(4)));
typedef unsigned short u16x8 __attribute__((ext_vector_type(8)));
typedef unsigned int u32x4 __attribute__((ext_vector_type(4)));

#define AS1 __attribute__((address_space(1)))
#define AS3 __attribute__((address_space(3)))

__device__ __forceinline__ void gload16(const void* g, void* l) {
    // async global->LDS, 16B per lane; LDS dest = wave-uniform base + lane*16
    __builtin_amdgcn_global_load_lds((AS1 unsigned int*)(unsigned long long)g,
                                     (AS3 unsigned int*)l, 16, 0, 0);
}

__device__ __forceinline__ unsigned short f2b(float f) {  // f32 -> bf16 RNE
    unsigned u = __builtin_bit_cast(unsigned, f);
    return (unsigned short)((u + 0x7fffu + ((u >> 16) & 1u)) >> 16);
}
__device__ __forceinline__ float b2f(unsigned short h) {
    return __builtin_bit_cast(float, ((unsigned)h) << 16);
}

static constexpr int HW = 16384;

// ---------------------------------------------------------------------------
// zero borders of 9 padded NHWC buffers (X*: C=64, F*/G*: C=128)
// ---------------------------------------------------------------------------
__global__ __launch_bounds__(256) void zero_borders_kernel(
    unsigned short* X0, unsigned short* X1, unsigned short* X2,
    unsigned short* F0, unsigned short* F1, unsigned short* F2,
    unsigned short* G0, unsigned short* G1, unsigned short* G2)
{
    int z = blockIdx.z;
    unsigned short* p; int C;
    switch (z) {
        case 0: p = X0; C = 64; break;
        case 1: p = X1; C = 64; break;
        case 2: p = X2; C = 64; break;
        case 3: p = F0; C = 128; break;
        case 4: p = F1; C = 128; break;
        case 5: p = F2; C = 128; break;
        case 6: p = G0; C = 128; break;
        case 7: p = G1; C = 128; break;
        default: p = G2; C = 128; break;
    }
    int chunks = C >> 3;
    int total = 2 * 516 * chunks;
    int idx = blockIdx.x * 256 + threadIdx.x;
    if (idx >= total) return;
    int cb = idx % chunks;
    int pidx = idx / chunks;
    int n = pidx / 516;
    int b = pidx % 516;
    int y, x;
    if (b < 130)      { y = 0;       x = b; }
    else if (b < 260) { y = 129;     x = b - 130; }
    else if (b < 388) { y = b - 259; x = 0; }
    else              { y = b - 387; x = 129; }
    u32x4 zz = {0u, 0u, 0u, 0u};
    *(u32x4*)(p + ((size_t)((n * 130 + y) * 130 + x)) * C + cb * 8) = zz;
}

// zero borders of one C=128 padded buffer (A1p, after X region is dead)
__global__ __launch_bounds__(256) void zero_one_kernel(unsigned short* p)
{
    int idx = blockIdx.x * 256 + threadIdx.x;
    if (idx >= 2 * 516 * 16) return;
    int cb = idx & 15;
    int pidx = idx >> 4;
    int n = pidx / 516;
    int b = pidx % 516;
    int y, x;
    if (b < 130)      { y = 0;       x = b; }
    else if (b < 260) { y = 129;     x = b - 130; }
    else if (b < 388) { y = b - 259; x = 0; }
    else              { y = b - 387; x = 129; }
    u32x4 zz = {0u, 0u, 0u, 0u};
    *(u32x4*)(p + ((size_t)((n * 130 + y) * 130 + x)) * 128 + cb * 8) = zz;
}

// ---------------------------------------------------------------------------
// pack weights into MFMA A-fragment order: [tap][kc][m][lane][8 bf16]
//   lane l of fragment (m): co = m*16 + (l&15), ci = kc*32 + (l>>4)*8 + j
// z: 0=W0p(conv0+adj tap), 1=W1p(conv1+identity tap), 2=Wqp, 3=Wkvp, 4=Wpoolp,
//    5=bias precompute (b0sum, s1, t1)
// ---------------------------------------------------------------------------
__global__ __launch_bounds__(256) void pack_kernel(
    const float* Wc0, const float* Wadj, const float* Wc1,
    const float* Wq, const float* Wkv, const float* Wpool,
    const float* bc0, const float* badj,
    const float* g1, const float* be1, const float* m1, const float* v1,
    unsigned short* W0p, unsigned short* W1p, unsigned short* Wqp,
    unsigned short* Wkvp, unsigned short* Wpp,
    float* b0sum, float* s1a, float* t1a)
{
    int z = blockIdx.z;
    int idx = blockIdx.x * 256 + threadIdx.x;
    if (z == 5) {
        if (idx < 128) {
            int co = idx;
            b0sum[co] = bc0[co] + badj[co];
            float s = g1[co] * rsqrtf(v1[co] + 1e-5f);
            s1a[co] = s;
            t1a[co] = be1[co] - m1[co] * s;
        }
        return;
    }
    int CIN, NTAP; unsigned short* dst;
    switch (z) {
        case 0: CIN = 64;  NTAP = 10; dst = W0p;  break;
        case 1: CIN = 128; NTAP = 10; dst = W1p;  break;
        case 2: CIN = 128; NTAP = 1;  dst = Wqp;  break;
        case 3: CIN = 128; NTAP = 1;  dst = Wkvp; break;
        default: CIN = 128; NTAP = 9; dst = Wpp;  break;
    }
    int KCN = CIN / 32;
    int count = NTAP * KCN * 512;
    if (idx >= count) return;
    int lane = idx & 63;
    int m = (idx >> 6) & 7;
    int rest = idx >> 9;
    int kc = rest % KCN;
    int tap = rest / KCN;
    int co = m * 16 + (lane & 15);
    int cib = kc * 32 + ((lane >> 4) << 3);
    unsigned short vals[8];
#pragma unroll
    for (int j = 0; j < 8; ++j) {
        int ci = cib + j;
        float v;
        if (z == 0)       v = (tap < 9) ? Wc0[((size_t)co * 64 + ci) * 9 + tap] : Wadj[co * 64 + ci];
        else if (z == 1)  v = (tap < 9) ? Wc1[((size_t)co * 128 + ci) * 9 + tap] : (co == ci ? 1.0f : 0.0f);
        else if (z == 2)  v = Wq[co * 128 + ci];
        else if (z == 3)  v = Wkv[co * 128 + ci];
        else              v = Wpool[((size_t)co * 128 + ci) * 9 + tap];
        vals[j] = f2b(v);
    }
    u32x4 pk;
    pk.x = vals[0] | ((unsigned)vals[1] << 16);
    pk.y = vals[2] | ((unsigned)vals[3] << 16);
    pk.z = vals[4] | ((unsigned)vals[5] << 16);
    pk.w = vals[6] | ((unsigned)vals[7] << 16);
    *(u32x4*)(dst + (size_t)idx * 8) = pk;
}

// ---------------------------------------------------------------------------
// prep: BN0 + pad + NCHW f32 -> NHWC bf16 padded (2,130,130,64), interior only
// grid (128 y, 6 = map*2+n), block 256
// ---------------------------------------------------------------------------
__global__ __launch_bounds__(256) void prep_kernel(
    const float* x0, const float* x1, const float* x2,
    const float* g0, const float* be0, const float* me0, const float* va0,
    unsigned short* X0, unsigned short* X1, unsigned short* X2)
{
    const int y = blockIdx.x;
    const int mz = blockIdx.y;
    const int map = mz >> 1, n = mz & 1;
    const float* in = (map == 0 ? x0 : map == 1 ? x1 : x2) + (size_t)n * 64 * HW + y * 128;
    unsigned short* out = (map == 0 ? X0 : map == 1 ? X1 : X2)
                          + ((size_t)(n * 130 + y + 1) * 130 + 1) * 64;
    const int x = threadIdx.x & 127;
    for (int cb = threadIdx.x >> 7; cb < 8; cb += 2) {
        unsigned short vals[8];
#pragma unroll
        for (int j = 0; j < 8; ++j) {
            int ci = cb * 8 + j;
            float s = g0[ci] * rsqrtf(va0[ci] + 1e-5f);
            float t = be0[ci] - me0[ci] * s;
            vals[j] = f2b(in[(size_t)ci * HW + x] * s + t);
        }
        u32x4 pk;
        pk.x = vals[0] | ((unsigned)vals[1] << 16);
        pk.y = vals[2] | ((unsigned)vals[3] << 16);
        pk.z = vals[4] | ((unsigned)vals[5] << 16);
        pk.w = vals[6] | ((unsigned)vals[7] << 16);
        *(u32x4*)(out + (size_t)x * 64 + cb * 8) = pk;
    }
}

// ---------------------------------------------------------------------------
// conv3: 3x3 conv (+residual tap) as implicit GEMM, NHWC padded in/out.
// EPI 0: F = bn1(lrelu(acc + b0sum))   EPI 1: G = lrelu(acc + bconv1)
// grid (2 co-half, 128 y, 6 = map*2+n), block 256 (4 waves, wave = 32 px)
// ---------------------------------------------------------------------------
template <int CIN, int EPI>
__global__ __launch_bounds__(256, 4) void conv3_kernel(
    const unsigned short* I0, const unsigned short* I1, const unsigned short* I2,
    const unsigned short* Wp, const float* bA, const float* bB, const float* bC,
    unsigned short* O0, unsigned short* O1, unsigned short* O2)
{
    constexpr int KCN = CIN / 32;
    constexpr int TKY[10] = {0,0,0,1,1,1,2,2,2,1};
    constexpr int TKX[10] = {0,1,2,0,1,2,0,1,2,1};
    const int tid = threadIdx.x;
    const int lane = tid & 63;
    const int l15 = lane & 15, l4 = lane >> 4;
    const int wv = tid >> 6;
    const int ch = blockIdx.x;
    const int y = blockIdx.y;
    const int mz = blockIdx.z;
    const int map = mz >> 1, n = mz & 1;
    const unsigned short* In = (map == 0 ? I0 : map == 1 ? I1 : I2) + (size_t)n * 130 * 130 * CIN;
    unsigned short* On = (map == 0 ? O0 : map == 1 ? O1 : O2) + (size_t)n * 130 * 130 * 128;

    __shared__ __align__(16) unsigned short stage[3 * 130 * 4 * 8];  // 24,960 B

    f32x4 acc[4][2];
#pragma unroll
    for (int a = 0; a < 4; ++a)
#pragma unroll
        for (int b = 0; b < 2; ++b) acc[a][b] = (f32x4){0.f, 0.f, 0.f, 0.f};

    const int px0 = wv * 32;
    const u32x4* Ap = (const u32x4*)Wp;

    for (int kc = 0; kc < KCN; ++kc) {
        if (kc) __syncthreads();
        // stage 3 rows x 130 x 32ci bf16, source pre-swizzled so ds_read is ~conflict-free
        for (int idx = tid; idx < 1560; idx += 256) {
            int r = idx / 520;
            int rem = idx - r * 520;
            int xx = rem >> 2;
            int slot = rem & 3;
            int cd = slot ^ ((xx >> 1) & 3);
            const unsigned short* src = In + ((size_t)(y + r) * 130 + xx) * CIN + kc * 32 + cd * 8;
            gload16(src, stage + (size_t)(idx & ~63) * 8);
        }
        __syncthreads();
#pragma unroll
        for (int t = 0; t < 10; ++t) {
            const int ky = TKY[t], kx = TKX[t];
            u32x4 a[4];
#pragma unroll
            for (int mi = 0; mi < 4; ++mi)
                a[mi] = Ap[((size_t)(t * KCN + kc) * 8 + ch * 4 + mi) * 64 + lane];
            bf16x8 bv[2];
#pragma unroll
            for (int nf = 0; nf < 2; ++nf) {
                int xx = px0 + nf * 16 + l15 + kx;
                int slot = l4 ^ ((xx >> 1) & 3);
                bv[nf] = *(const bf16x8*)(stage + ((size_t)(ky * 130 + xx) * 4 + slot) * 8);
            }
#pragma unroll
            for (int mi = 0; mi < 4; ++mi) {
                bf16x8 av = __builtin_bit_cast(bf16x8, a[mi]);
#pragma unroll
                for (int nf = 0; nf < 2; ++nf)
                    acc[mi][nf] = __builtin_amdgcn_mfma_f32_16x16x32_bf16(av, bv[nf], acc[mi][nf], 0, 0, 0);
            }
        }
    }
    // epilogue: bias + lrelu (+ BN1 fold for EPI 0), store NHWC bf16 interior
#pragma unroll
    for (int mi = 0; mi < 4; ++mi) {
#pragma unroll
        for (int nf = 0; nf < 2; ++nf) {
            int px = px0 + nf * 16 + l15;
            int cobase = (ch * 4 + mi) * 16 + l4 * 4;
            float t4[4];
#pragma unroll
            for (int r = 0; r < 4; ++r) {
                int co = cobase + r;
                float v = acc[mi][nf][r] + bA[co];
                v = v > 0.f ? v : 0.05f * v;
                if (EPI == 0) v = v * bB[co] + bC[co];
                t4[r] = v;
            }
            unsigned short* op = On + ((size_t)(y + 1) * 130 + (px + 1)) * 128 + cobase;
            *(unsigned*)(op)     = (unsigned)f2b(t4[0]) | ((unsigned)f2b(t4[1]) << 16);
            *(unsigned*)(op + 2) = (unsigned)f2b(t4[2]) | ((unsigned)f2b(t4[3]) << 16);
        }
    }
}

// ---------------------------------------------------------------------------
// proj: 1x1 conv GEMM. z: 0 = G0->KV0 (rows 0..129), 1 = G2->KV2, 2 = G1->Qb
// grid (2 co-half, 130 yy, 6 = proj*2+n), block 256
// ---------------------------------------------------------------------------
__global__ __launch_bounds__(256, 4) void proj_kernel(
    const unsigned short* G0, const unsigned short* G1, const unsigned short* G2,
    const unsigned short* Wqp, const unsigned short* Wkvp,
    const float* bq, const float* bkv,
    unsigned short* KV0, unsigned short* KV2, unsigned short* Qb)
{
    const int z = blockIdx.z;
    const int proj = z >> 1, n = z & 1;
    const int yy = blockIdx.y;
    if (proj == 2 && (yy == 0 || yy == 129)) return;
    const int tid = threadIdx.x;
    const int lane = tid & 63, l15 = lane & 15, l4 = lane >> 4, wv = tid >> 6;
    const int ch = blockIdx.x;
    const unsigned short* In = (proj == 0 ? G0 : proj == 1 ? G2 : G1) + (size_t)n * 130 * 130 * 128;
    const unsigned short* Wp = (proj == 2) ? Wqp : Wkvp;
    const float* bias = (proj == 2) ? bq : bkv;

    __shared__ __align__(16) unsigned short stage[130 * 4 * 8];

    f32x4 acc[4][2];
#pragma unroll
    for (int a = 0; a < 4; ++a)
#pragma unroll
        for (int b = 0; b < 2; ++b) acc[a][b] = (f32x4){0.f, 0.f, 0.f, 0.f};

    const int px0 = wv * 32;
    const u32x4* Ap = (const u32x4*)Wp;

    for (int kc = 0; kc < 4; ++kc) {
        if (kc) __syncthreads();
        for (int idx = tid; idx < 520; idx += 256) {
            int xx = idx >> 2, slot = idx & 3;
            int cd = slot ^ ((xx >> 1) & 3);
            gload16(In + ((size_t)yy * 130 + xx) * 128 + kc * 32 + cd * 8,
                    stage + (size_t)(idx & ~63) * 8);
        }
        __syncthreads();
        u32x4 a[4];
#pragma unroll
        for (int mi = 0; mi < 4; ++mi)
            a[mi] = Ap[((size_t)kc * 8 + ch * 4 + mi) * 64 + lane];
        bf16x8 bv[2];
#pragma unroll
        for (int nf = 0; nf < 2; ++nf) {
            int xx = px0 + nf * 16 + l15 + 1;
            int slot = l4 ^ ((xx >> 1) & 3);
            bv[nf] = *(const bf16x8*)(stage + ((size_t)xx * 4 + slot) * 8);
        }
#pragma unroll
        for (int mi = 0; mi < 4; ++mi) {
            bf16x8 av = __builtin_bit_cast(bf16x8, a[mi]);
#pragma unroll
            for (int nf = 0; nf < 2; ++nf)
                acc[mi][nf] = __builtin_amdgcn_mfma_f32_16x16x32_bf16(av, bv[nf], acc[mi][nf], 0, 0, 0);
        }
        if (kc < 3) __syncthreads();
    }
#pragma unroll
    for (int mi = 0; mi < 4; ++mi) {
#pragma unroll
        for (int nf = 0; nf < 2; ++nf) {
            int px = px0 + nf * 16 + l15;
            int cobase = (ch * 4 + mi) * 16 + l4 * 4;
            float t4[4];
#pragma unroll
            for (int r = 0; r < 4; ++r) t4[r] = acc[mi][nf][r] + bias[cobase + r];
            unsigned short* op;
            if (proj == 2)
                op = Qb + ((size_t)(n * 128 + yy - 1) * 128 + px) * 128 + cobase;
            else
                op = (proj == 0 ? KV0 : KV2) + ((size_t)(n * 130 + yy) * 130 + (px + 1)) * 128 + cobase;
            *(unsigned*)(op)     = (unsigned)f2b(t4[0]) | ((unsigned)f2b(t4[1]) << 16);
            *(unsigned*)(op + 2) = (unsigned)f2b(t4[2]) | ((unsigned)f2b(t4[3]) << 16);
        }
    }
}

// KV border columns (x = 0 / 129) = bias
__global__ __launch_bounds__(256) void kv_border_kernel(
    unsigned short* KV0, unsigned short* KV2, const float* bkv)
{
    int idx = blockIdx.x * 256 + threadIdx.x;
    if (idx >= 16640) return;
    int cb = idx & 15;
    int t = idx >> 4;
    int col = t & 1; t >>= 1;
    int yy = t % 130; t /= 130;
    int n = t & 1;
    int buf = t >> 1;
    unsigned short* p = (buf ? KV2 : KV0)
        + ((size_t)(n * 130 + yy) * 130 + (col ? 129 : 0)) * 128 + cb * 8;
    u16x8 v;
#pragma unroll
    for (int j = 0; j < 8; ++j) v[j] = f2b(bkv[cb * 8 + j]);
    *(u16x8*)p = v;
}

// ---------------------------------------------------------------------------
// attention: both branches fused. grid (128 y, 2 n, 4 h), block 128.
// out: pass (f32 NCHW) and A1p (bf16 NHWC padded, for pooling)
// ---------------------------------------------------------------------------
__global__ void attn_kernel(const unsigned short* Qb, const unsigned short* KV0,
                            const unsigned short* KV2, float* pass, unsigned short* A1p)
{
    const int y = blockIdx.x, n = blockIdx.y, h = blockIdx.z;
    const int tid = threadIdx.x;   // 0..127 = pixel x
    const int x = tid;
    __shared__ __align__(16) unsigned short k0[12480], k1[12480];
    for (int idx = tid; idx < 1560; idx += 128) {
        int r = idx / 520;
        int rem = idx - r * 520;
        int xx = rem >> 2;
        int slot = rem & 3;
        int cd = slot ^ ((xx >> 1) & 3);
        size_t go = ((size_t)(n * 130 + y + r) * 130 + xx) * 128 + h * 32 + cd * 8;
        gload16(KV0 + go, k0 + (size_t)(idx & ~63) * 8);
        gload16(KV2 + go, k1 + (size_t)(idx & ~63) * 8);
    }
    __syncthreads();

    const u16x8* qp = (const u16x8*)(Qb + ((size_t)(n * 128 + y) * 128 + x) * 128 + h * 32);
    u16x8 q8[4];
#pragma unroll
    for (int d8 = 0; d8 < 4; ++d8) q8[d8] = qp[d8];

    float lg0[9], lg1[9];
#pragma unroll
    for (int t = 0; t < 9; ++t) { lg0[t] = 0.f; lg1[t] = 0.f; }
#pragma unroll
    for (int d8 = 0; d8 < 4; ++d8) {
        float qf[8];
#pragma unroll
        for (int j = 0; j < 8; ++j) qf[j] = b2f(q8[d8][j]);
#pragma unroll
        for (int t = 0; t < 9; ++t) {
            int ky = t / 3, kx = t % 3;
            int xp = x + kx;
            int off = ((ky * 130 + xp) * 4 + (d8 ^ ((xp >> 1) & 3))) * 8;
            u16x8 a = *(const u16x8*)(k0 + off);
            u16x8 c = *(const u16x8*)(k1 + off);
#pragma unroll
            for (int j = 0; j < 8; ++j) {
                lg0[t] += qf[j] * b2f(a[j]);
                lg1[t] += qf[j] * b2f(c[j]);
            }
        }
    }
    const float SC = 0.17677669529663687f;
    float w0[9], w1[9];
    float m0v = -1e30f, m1v = -1e30f;
#pragma unroll
    for (int t = 0; t < 9; ++t) {
        lg0[t] *= SC; lg1[t] *= SC;
        m0v = fmaxf(m0v, lg0[t]); m1v = fmaxf(m1v, lg1[t]);
    }
    float s0 = 0.f, s1 = 0.f;
#pragma unroll
    for (int t = 0; t < 9; ++t) {
        w0[t] = __expf(lg0[t] - m0v); s0 += w0[t];
        w1[t] = __expf(lg1[t] - m1v); s1 += w1[t];
    }
    float r0 = 0.5f / s0, r1 = 0.5f / s1;
#pragma unroll
    for (int t = 0; t < 9; ++t) { w0[t] *= r0; w1[t] *= r1; }

    float o[32];
#pragma unroll
    for (int d = 0; d < 32; ++d) o[d] = 0.f;
#pragma unroll
    for (int d8 = 0; d8 < 4; ++d8) {
#pragma unroll
        for (int t = 0; t < 9; ++t) {
            int ky = t / 3, kx = t % 3;
            int xp = x + kx;
            int off = ((ky * 130 + xp) * 4 + (d8 ^ ((xp >> 1) & 3))) * 8;
            u16x8 a = *(const u16x8*)(k0 + off);
            u16x8 c = *(const u16x8*)(k1 + off);
#pragma unroll
            for (int j = 0; j < 8; ++j)
                o[d8 * 8 + j] += w0[t] * b2f(a[j]) + w1[t] * b2f(c[j]);
        }
    }
    // pass: f32 NCHW
    float* pp = pass + ((size_t)(n * 128 + h * 32) * 128 + y) * 128 + x;
#pragma unroll
    for (int d = 0; d < 32; ++d) pp[(size_t)d * HW] = o[d];
    // A1p: bf16 NHWC padded
    unsigned short* ap = A1p + ((size_t)(n * 130 + y + 1) * 130 + (x + 1)) * 128 + h * 32;
#pragma unroll
    for (int d8 = 0; d8 < 4; ++d8) {
        u16x8 v;
#pragma unroll
        for (int j = 0; j < 8; ++j) v[j] = f2b(o[d8 * 8 + j]);
        *(u16x8*)(ap + d8 * 8) = v;
    }
}

// ---------------------------------------------------------------------------
// pool: 3x3 stride-2 conv, NHWC padded bf16 in -> f32 NCHW out (2,128,64,64)
// grid (2 co-half, 64 yo, 6 = map*2+n), block 256 (4 waves, 16 px each)
// ---------------------------------------------------------------------------
__global__ __launch_bounds__(256, 4) void pool_kernel(
    const unsigned short* G0, const unsigned short* A1, const unsigned short* G2,
    const unsigned short* Wpp, const float* bp, float* out)
{
    const int z = blockIdx.z;
    const int map = z >> 1, n = z & 1;
    const int yo = blockIdx.y;
    const int ch = blockIdx.x;
    const int tid = threadIdx.x, lane = tid & 63, l15 = lane & 15, l4 = lane >> 4, wv = tid >> 6;
    const unsigned short* In = (map == 0 ? G0 : map == 1 ? A1 : G2) + (size_t)n * 130 * 130 * 128;
    float* outp = out + (size_t)map * 1048576 + (size_t)n * 524288;

    __shared__ __align__(16) unsigned short stage[3 * 130 * 4 * 8];

    f32x4 acc[4];
#pragma unroll
    for (int a = 0; a < 4; ++a) acc[a] = (f32x4){0.f, 0.f, 0.f, 0.f};

    const int px0 = wv * 16;
    const u32x4* Ap = (const u32x4*)Wpp;

    for (int kc = 0; kc < 4; ++kc) {
        if (kc) __syncthreads();
        for (int idx = tid; idx < 1560; idx += 256) {
            int r = idx / 520;
            int rem = idx - r * 520;
            int xx = rem >> 2;
            int slot = rem & 3;
            int cd = slot ^ ((xx >> 1) & 3);
            gload16(In + ((size_t)(2 * yo + r) * 130 + xx) * 128 + kc * 32 + cd * 8,
                    stage + (size_t)(idx & ~63) * 8);
        }
        __syncthreads();
#pragma unroll
        for (int t = 0; t < 9; ++t) {
            const int ky = t / 3, kx = t % 3;
            u32x4 a[4];
#pragma unroll
            for (int mi = 0; mi < 4; ++mi)
                a[mi] = Ap[((size_t)(t * 4 + kc) * 8 + ch * 4 + mi) * 64 + lane];
            int xx = 2 * (px0 + l15) + kx;
            int slot = l4 ^ ((xx >> 1) & 3);
            bf16x8 bv = *(const bf16x8*)(stage + ((size_t)(ky * 130 + xx) * 4 + slot) * 8);
#pragma unroll
            for (int mi = 0; mi < 4; ++mi)
                acc[mi] = __builtin_amdgcn_mfma_f32_16x16x32_bf16(
                    __builtin_bit_cast(bf16x8, a[mi]), bv, acc[mi], 0, 0, 0);
        }
    }
#pragma unroll
    for (int mi = 0; mi < 4; ++mi) {
        int cobase = (ch * 4 + mi) * 16 + l4 * 4;
        int px = px0 + l15;
#pragma unroll
        for (int r = 0; r < 4; ++r) {
            int co = cobase + r;
            outp[((size_t)co * 64 + yo) * 64 + px] = acc[mi][r] + bp[co];
        }
    }
}

// ---------------------------------------------------------------------------
extern "C" void kernel_launch(void* const* d_in, const int* in_sizes, int n_in,
                              void* d_out, int out_size, void* d_ws, size_t ws_size,
                              hipStream_t stream)
{
    const float* x0 = (const float*)d_in[0];
    const float* x1 = (const float*)d_in[1];
    const float* x2 = (const float*)d_in[2];
    const float* gamma0 = (const float*)d_in[3];
    const float* beta0  = (const float*)d_in[4];
    const float* mean0  = (const float*)d_in[5];
    const float* var0   = (const float*)d_in[6];
    const float* gamma1 = (const float*)d_in[7];
    const float* beta1  = (const float*)d_in[8];
    const float* mean1  = (const float*)d_in[9];
    const float* var1   = (const float*)d_in[10];
    const float* W_adj  = (const float*)d_in[11];
    const float* b_adj  = (const float*)d_in[12];
    const float* W_conv0 = (const float*)d_in[13];
    const float* b_conv0 = (const float*)d_in[14];
    const float* W_conv1 = (const float*)d_in[15];
    const float* b_conv1 = (const float*)d_in[16];
    const float* Wq  = (const float*)d_in[17];
    const float* bq  = (const float*)d_in[18];
    const float* Wkv = (const float*)d_in[19];
    const float* bkv = (const float*)d_in[20];
    const float* W_pool = (const float*)d_in[21];
    const float* b_pool = (const float*)d_in[22];

    float* out  = (float*)d_out;
    float* pass = out + 3145728;                 // (2,128,128,128) f32 NCHW

    char* wsb = (char*)d_ws;
    const size_t FSZ = 8652800;                  // 2*130*130*128*2 B
    const size_t XSZ = 4326400;                  // 2*130*130*64*2 B
    unsigned short* F0 = (unsigned short*)(wsb);
    unsigned short* F1 = (unsigned short*)(wsb + FSZ);
    unsigned short* F2 = (unsigned short*)(wsb + 2 * FSZ);
    unsigned short* G0 = (unsigned short*)(wsb + 3 * FSZ);
    unsigned short* G1 = (unsigned short*)(wsb + 4 * FSZ);
    unsigned short* G2 = (unsigned short*)(wsb + 5 * FSZ);
    unsigned short* X0 = (unsigned short*)(wsb + 6 * FSZ);
    unsigned short* X1 = (unsigned short*)(wsb + 6 * FSZ + XSZ);
    unsigned short* X2 = (unsigned short*)(wsb + 6 * FSZ + 2 * XSZ);
    char* WAR = wsb + 6 * FSZ + 3 * XSZ;
    unsigned short* W0p    = (unsigned short*)(WAR);
    unsigned short* W1p    = (unsigned short*)(WAR + 163840);
    unsigned short* Wqp    = (unsigned short*)(WAR + 491520);
    unsigned short* Wkvp   = (unsigned short*)(WAR + 524288);
    unsigned short* Wpoolp = (unsigned short*)(WAR + 557056);
    float* b0sum = (float*)(WAR + 851968);
    float* s1a   = (float*)(WAR + 852480);
    float* t1a   = (float*)(WAR + 852992);
    // aliases (lifetimes disjoint, stream-ordered)
    unsigned short* KV0 = F0;
    unsigned short* KV2 = F1;
    unsigned short* Qb  = F2;
    unsigned short* A1p = X0;   // spans X0+X1

    zero_borders_kernel<<<dim3(65, 1, 9), 256, 0, stream>>>(X0, X1, X2, F0, F1, F2, G0, G1, G2);
    pack_kernel<<<dim3(80, 1, 6), 256, 0, stream>>>(
        W_conv0, W_adj, W_conv1, Wq, Wkv, W_pool, b_conv0, b_adj,
        gamma1, beta1, mean1, var1, W0p, W1p, Wqp, Wkvp, Wpoolp, b0sum, s1a, t1a);
    prep_kernel<<<dim3(128, 6), 256, 0, stream>>>(
        x0, x1, x2, gamma0, beta0, mean0, var0, X0, X1, X2);

    conv3_kernel<64, 0><<<dim3(2, 128, 6), 256, 0, stream>>>(
        X0, X1, X2, W0p, b0sum, s1a, t1a, F0, F1, F2);
    conv3_kernel<128, 1><<<dim3(2, 128, 6), 256, 0, stream>>>(
        F0, F1, F2, W1p, b_conv1, nullptr, nullptr, G0, G1, G2);

    zero_one_kernel<<<dim3(65), 256, 0, stream>>>(A1p);
    proj_kernel<<<dim3(2, 130, 6), 256, 0, stream>>>(
        G0, G1, G2, Wqp, Wkvp, bq, bkv, KV0, KV2, Qb);
    kv_border_kernel<<<dim3(65), 256, 0, stream>>>(KV0, KV2, bkv);

    attn_kernel<<<dim3(128, 2, 4), 128, 0, stream>>>(Qb, KV0, KV2, pass, A1p);

    pool_kernel<<<dim3(2, 64, 6), 256, 0, stream>>>(G0, A1p, G2, Wpoolp, b_pool, out);
}

// Round 3
// 400.101 us; speedup vs baseline: 4.9385x; 1.2908x over previous
//
#include <hip/hip_runtime.h>
#include <cstdint>
#include <cstddef>

// ---------------------------------------------------------------------------
// Types / helpers
// ---------------------------------------------------------------------------
typedef __bf16 bf16x8 __attribute__((ext_vector_type(8)));
typedef float f32x4 __attribute__((ext_vector_type(4)));
typedef unsigned short u16x8 __attribute__((ext_vector_type(8)));
typedef unsigned int u32x4 __attribute__((ext_vector_type(4)));

#define AS1 __attribute__((address_space(1)))
#define AS3 __attribute__((address_space(3)))

__device__ __forceinline__ void gload16(const void* g, void* l) {
    // async global->LDS, 16B per lane; LDS dest = wave-uniform base + lane*16
    __builtin_amdgcn_global_load_lds((AS1 unsigned int*)(unsigned long long)g,
                                     (AS3 unsigned int*)l, 16, 0, 0);
}

__device__ __forceinline__ unsigned short f2b(float f) {  // f32 -> bf16 RNE
    unsigned u = __builtin_bit_cast(unsigned, f);
    return (unsigned short)((u + 0x7fffu + ((u >> 16) & 1u)) >> 16);
}
__device__ __forceinline__ float b2f(unsigned short h) {
    return __builtin_bit_cast(float, ((unsigned)h) << 16);
}

static constexpr int HW = 16384;

// ---------------------------------------------------------------------------
// zero borders of 9 padded NHWC buffers (X*: C=64, F*/G*: C=128)
// ---------------------------------------------------------------------------
__global__ __launch_bounds__(256) void zero_borders_kernel(
    unsigned short* X0, unsigned short* X1, unsigned short* X2,
    unsigned short* F0, unsigned short* F1, unsigned short* F2,
    unsigned short* G0, unsigned short* G1, unsigned short* G2)
{
    int z = blockIdx.z;
    unsigned short* p; int C;
    switch (z) {
        case 0: p = X0; C = 64; break;
        case 1: p = X1; C = 64; break;
        case 2: p = X2; C = 64; break;
        case 3: p = F0; C = 128; break;
        case 4: p = F1; C = 128; break;
        case 5: p = F2; C = 128; break;
        case 6: p = G0; C = 128; break;
        case 7: p = G1; C = 128; break;
        default: p = G2; C = 128; break;
    }
    int chunks = C >> 3;
    int total = 2 * 516 * chunks;
    int idx = blockIdx.x * 256 + threadIdx.x;
    if (idx >= total) return;
    int cb = idx % chunks;
    int pidx = idx / chunks;
    int n = pidx / 516;
    int b = pidx % 516;
    int y, x;
    if (b < 130)      { y = 0;       x = b; }
    else if (b < 260) { y = 129;     x = b - 130; }
    else if (b < 388) { y = b - 259; x = 0; }
    else              { y = b - 387; x = 129; }
    u32x4 zz = {0u, 0u, 0u, 0u};
    *(u32x4*)(p + ((size_t)((n * 130 + y) * 130 + x)) * C + cb * 8) = zz;
}

// zero borders of one C=128 padded buffer (A1p, after X region is dead)
__global__ __launch_bounds__(256) void zero_one_kernel(unsigned short* p)
{
    int idx = blockIdx.x * 256 + threadIdx.x;
    if (idx >= 2 * 516 * 16) return;
    int cb = idx & 15;
    int pidx = idx >> 4;
    int n = pidx / 516;
    int b = pidx % 516;
    int y, x;
    if (b < 130)      { y = 0;       x = b; }
    else if (b < 260) { y = 129;     x = b - 130; }
    else if (b < 388) { y = b - 259; x = 0; }
    else              { y = b - 387; x = 129; }
    u32x4 zz = {0u, 0u, 0u, 0u};
    *(u32x4*)(p + ((size_t)((n * 130 + y) * 130 + x)) * 128 + cb * 8) = zz;
}

// ---------------------------------------------------------------------------
// pack weights into MFMA A-fragment order: [tap][kc][m][lane][8 bf16]
//   lane l of fragment (m): co = m*16 + (l&15), ci = kc*32 + (l>>4)*8 + j
// z: 0=W0p(conv0+adj tap), 1=W1p(conv1+identity tap), 2=Wqp, 3=Wkvp, 4=Wpoolp,
//    5=bias precompute (b0sum, s1, t1)
// ---------------------------------------------------------------------------
__global__ __launch_bounds__(256) void pack_kernel(
    const float* Wc0, const float* Wadj, const float* Wc1,
    const float* Wq, const float* Wkv, const float* Wpool,
    const float* bc0, const float* badj,
    const float* g1, const float* be1, const float* m1, const float* v1,
    unsigned short* W0p, unsigned short* W1p, unsigned short* Wqp,
    unsigned short* Wkvp, unsigned short* Wpp,
    float* b0sum, float* s1a, float* t1a)
{
    int z = blockIdx.z;
    int idx = blockIdx.x * 256 + threadIdx.x;
    if (z == 5) {
        if (idx < 128) {
            int co = idx;
            b0sum[co] = bc0[co] + badj[co];
            float s = g1[co] * rsqrtf(v1[co] + 1e-5f);
            s1a[co] = s;
            t1a[co] = be1[co] - m1[co] * s;
        }
        return;
    }
    int CIN, NTAP; unsigned short* dst;
    switch (z) {
        case 0: CIN = 64;  NTAP = 10; dst = W0p;  break;
        case 1: CIN = 128; NTAP = 10; dst = W1p;  break;
        case 2: CIN = 128; NTAP = 1;  dst = Wqp;  break;
        case 3: CIN = 128; NTAP = 1;  dst = Wkvp; break;
        default: CIN = 128; NTAP = 9; dst = Wpp;  break;
    }
    int KCN = CIN / 32;
    int count = NTAP * KCN * 512;
    if (idx >= count) return;
    int lane = idx & 63;
    int m = (idx >> 6) & 7;
    int rest = idx >> 9;
    int kc = rest % KCN;
    int tap = rest / KCN;
    int co = m * 16 + (lane & 15);
    int cib = kc * 32 + ((lane >> 4) << 3);
    unsigned short vals[8];
#pragma unroll
    for (int j = 0; j < 8; ++j) {
        int ci = cib + j;
        float v;
        if (z == 0)       v = (tap < 9) ? Wc0[((size_t)co * 64 + ci) * 9 + tap] : Wadj[co * 64 + ci];
        else if (z == 1)  v = (tap < 9) ? Wc1[((size_t)co * 128 + ci) * 9 + tap] : (co == ci ? 1.0f : 0.0f);
        else if (z == 2)  v = Wq[co * 128 + ci];
        else if (z == 3)  v = Wkv[co * 128 + ci];
        else              v = Wpool[((size_t)co * 128 + ci) * 9 + tap];
        vals[j] = f2b(v);
    }
    u32x4 pk;
    pk.x = vals[0] | ((unsigned)vals[1] << 16);
    pk.y = vals[2] | ((unsigned)vals[3] << 16);
    pk.z = vals[4] | ((unsigned)vals[5] << 16);
    pk.w = vals[6] | ((unsigned)vals[7] << 16);
    *(u32x4*)(dst + (size_t)idx * 8) = pk;
}

// ---------------------------------------------------------------------------
// prep: BN0 + pad + NCHW f32 -> NHWC bf16 padded (2,130,130,64), interior only
// grid (128 y, 6 = map*2+n), block 256
// ---------------------------------------------------------------------------
__global__ __launch_bounds__(256) void prep_kernel(
    const float* x0, const float* x1, const float* x2,
    const float* g0, const float* be0, const float* me0, const float* va0,
    unsigned short* X0, unsigned short* X1, unsigned short* X2)
{
    const int y = blockIdx.x;
    const int mz = blockIdx.y;
    const int map = mz >> 1, n = mz & 1;
    const float* in = (map == 0 ? x0 : map == 1 ? x1 : x2) + (size_t)n * 64 * HW + y * 128;
    unsigned short* out = (map == 0 ? X0 : map == 1 ? X1 : X2)
                          + ((size_t)(n * 130 + y + 1) * 130 + 1) * 64;
    const int x = threadIdx.x & 127;
    for (int cb = threadIdx.x >> 7; cb < 8; cb += 2) {
        unsigned short vals[8];
#pragma unroll
        for (int j = 0; j < 8; ++j) {
            int ci = cb * 8 + j;
            float s = g0[ci] * rsqrtf(va0[ci] + 1e-5f);
            float t = be0[ci] - me0[ci] * s;
            vals[j] = f2b(in[(size_t)ci * HW + x] * s + t);
        }
        u32x4 pk;
        pk.x = vals[0] | ((unsigned)vals[1] << 16);
        pk.y = vals[2] | ((unsigned)vals[3] << 16);
        pk.z = vals[4] | ((unsigned)vals[5] << 16);
        pk.w = vals[6] | ((unsigned)vals[7] << 16);
        *(u32x4*)(out + (size_t)x * 64 + cb * 8) = pk;
    }
}

// ---------------------------------------------------------------------------
// conv3: 3x3 conv (+residual tap) as implicit GEMM, NHWC padded in/out.
// EPI 0: F = bn1(lrelu(acc + b0sum))   EPI 1: G = lrelu(acc + bconv1)
// grid (2 co-half, 128 y, 6 = map*2+n), block 256 (4 waves, wave = 32 px)
// ---------------------------------------------------------------------------
template <int CIN, int EPI>
__global__ __launch_bounds__(256, 4) void conv3_kernel(
    const unsigned short* I0, const unsigned short* I1, const unsigned short* I2,
    const unsigned short* Wp, const float* bA, const float* bB, const float* bC,
    unsigned short* O0, unsigned short* O1, unsigned short* O2)
{
    constexpr int KCN = CIN / 32;
    constexpr int TKY[10] = {0,0,0,1,1,1,2,2,2,1};
    constexpr int TKX[10] = {0,1,2,0,1,2,0,1,2,1};
    const int tid = threadIdx.x;
    const int lane = tid & 63;
    const int l15 = lane & 15, l4 = lane >> 4;
    const int wv = tid >> 6;
    const int ch = blockIdx.x;
    const int y = blockIdx.y;
    const int mz = blockIdx.z;
    const int map = mz >> 1, n = mz & 1;
    const unsigned short* In = (map == 0 ? I0 : map == 1 ? I1 : I2) + (size_t)n * 130 * 130 * CIN;
    unsigned short* On = (map == 0 ? O0 : map == 1 ? O1 : O2) + (size_t)n * 130 * 130 * 128;

    __shared__ __align__(16) unsigned short stage[3 * 130 * 4 * 8];  // 24,960 B

    f32x4 acc[4][2];
#pragma unroll
    for (int a = 0; a < 4; ++a)
#pragma unroll
        for (int b = 0; b < 2; ++b) acc[a][b] = (f32x4){0.f, 0.f, 0.f, 0.f};

    const int px0 = wv * 32;
    const u32x4* Ap = (const u32x4*)Wp;

    for (int kc = 0; kc < KCN; ++kc) {
        if (kc) __syncthreads();
        // stage 3 rows x 130 x 32ci bf16, source pre-swizzled so ds_read is ~conflict-free
        for (int idx = tid; idx < 1560; idx += 256) {
            int r = idx / 520;
            int rem = idx - r * 520;
            int xx = rem >> 2;
            int slot = rem & 3;
            int cd = slot ^ ((xx >> 1) & 3);
            const unsigned short* src = In + ((size_t)(y + r) * 130 + xx) * CIN + kc * 32 + cd * 8;
            gload16(src, stage + (size_t)(idx & ~63) * 8);
        }
        __syncthreads();
#pragma unroll
        for (int t = 0; t < 10; ++t) {
            const int ky = TKY[t], kx = TKX[t];
            u32x4 a[4];
#pragma unroll
            for (int mi = 0; mi < 4; ++mi)
                a[mi] = Ap[((size_t)(t * KCN + kc) * 8 + ch * 4 + mi) * 64 + lane];
            bf16x8 bv[2];
#pragma unroll
            for (int nf = 0; nf < 2; ++nf) {
                int xx = px0 + nf * 16 + l15 + kx;
                int slot = l4 ^ ((xx >> 1) & 3);
                bv[nf] = *(const bf16x8*)(stage + ((size_t)(ky * 130 + xx) * 4 + slot) * 8);
            }
#pragma unroll
            for (int mi = 0; mi < 4; ++mi) {
                bf16x8 av = __builtin_bit_cast(bf16x8, a[mi]);
#pragma unroll
                for (int nf = 0; nf < 2; ++nf)
                    acc[mi][nf] = __builtin_amdgcn_mfma_f32_16x16x32_bf16(av, bv[nf], acc[mi][nf], 0, 0, 0);
            }
        }
    }
    // epilogue: bias + lrelu (+ BN1 fold for EPI 0), store NHWC bf16 interior
#pragma unroll
    for (int mi = 0; mi < 4; ++mi) {
#pragma unroll
        for (int nf = 0; nf < 2; ++nf) {
            int px = px0 + nf * 16 + l15;
            int cobase = (ch * 4 + mi) * 16 + l4 * 4;
            float t4[4];
#pragma unroll
            for (int r = 0; r < 4; ++r) {
                int co = cobase + r;
                float v = acc[mi][nf][r] + bA[co];
                v = v > 0.f ? v : 0.05f * v;
                if (EPI == 0) v = v * bB[co] + bC[co];
                t4[r] = v;
            }
            unsigned short* op = On + ((size_t)(y + 1) * 130 + (px + 1)) * 128 + cobase;
            *(unsigned*)(op)     = (unsigned)f2b(t4[0]) | ((unsigned)f2b(t4[1]) << 16);
            *(unsigned*)(op + 2) = (unsigned)f2b(t4[2]) | ((unsigned)f2b(t4[3]) << 16);
        }
    }
}

// ---------------------------------------------------------------------------
// proj: 1x1 conv GEMM. z: 0 = G0->KV0 (rows 0..129), 1 = G2->KV2, 2 = G1->Qb
// grid (2 co-half, 130 yy, 6 = proj*2+n), block 256
// ---------------------------------------------------------------------------
__global__ __launch_bounds__(256, 4) void proj_kernel(
    const unsigned short* G0, const unsigned short* G1, const unsigned short* G2,
    const unsigned short* Wqp, const unsigned short* Wkvp,
    const float* bq, const float* bkv,
    unsigned short* KV0, unsigned short* KV2, unsigned short* Qb)
{
    const int z = blockIdx.z;
    const int proj = z >> 1, n = z & 1;
    const int yy = blockIdx.y;
    if (proj == 2 && (yy == 0 || yy == 129)) return;
    const int tid = threadIdx.x;
    const int lane = tid & 63, l15 = lane & 15, l4 = lane >> 4, wv = tid >> 6;
    const int ch = blockIdx.x;
    const unsigned short* In = (proj == 0 ? G0 : proj == 1 ? G2 : G1) + (size_t)n * 130 * 130 * 128;
    const unsigned short* Wp = (proj == 2) ? Wqp : Wkvp;
    const float* bias = (proj == 2) ? bq : bkv;

    __shared__ __align__(16) unsigned short stage[130 * 4 * 8];

    f32x4 acc[4][2];
#pragma unroll
    for (int a = 0; a < 4; ++a)
#pragma unroll
        for (int b = 0; b < 2; ++b) acc[a][b] = (f32x4){0.f, 0.f, 0.f, 0.f};

    const int px0 = wv * 32;
    const u32x4* Ap = (const u32x4*)Wp;

    for (int kc = 0; kc < 4; ++kc) {
        if (kc) __syncthreads();
        for (int idx = tid; idx < 520; idx += 256) {
            int xx = idx >> 2, slot = idx & 3;
            int cd = slot ^ ((xx >> 1) & 3);
            gload16(In + ((size_t)yy * 130 + xx) * 128 + kc * 32 + cd * 8,
                    stage + (size_t)(idx & ~63) * 8);
        }
        __syncthreads();
        u32x4 a[4];
#pragma unroll
        for (int mi = 0; mi < 4; ++mi)
            a[mi] = Ap[((size_t)kc * 8 + ch * 4 + mi) * 64 + lane];
        bf16x8 bv[2];
#pragma unroll
        for (int nf = 0; nf < 2; ++nf) {
            int xx = px0 + nf * 16 + l15 + 1;
            int slot = l4 ^ ((xx >> 1) & 3);
            bv[nf] = *(const bf16x8*)(stage + ((size_t)xx * 4 + slot) * 8);
        }
#pragma unroll
        for (int mi = 0; mi < 4; ++mi) {
            bf16x8 av = __builtin_bit_cast(bf16x8, a[mi]);
#pragma unroll
            for (int nf = 0; nf < 2; ++nf)
                acc[mi][nf] = __builtin_amdgcn_mfma_f32_16x16x32_bf16(av, bv[nf], acc[mi][nf], 0, 0, 0);
        }
        if (kc < 3) __syncthreads();
    }
#pragma unroll
    for (int mi = 0; mi < 4; ++mi) {
#pragma unroll
        for (int nf = 0; nf < 2; ++nf) {
            int px = px0 + nf * 16 + l15;
            int cobase = (ch * 4 + mi) * 16 + l4 * 4;
            float t4[4];
#pragma unroll
            for (int r = 0; r < 4; ++r) t4[r] = acc[mi][nf][r] + bias[cobase + r];
            unsigned short* op;
            if (proj == 2)
                op = Qb + ((size_t)(n * 128 + yy - 1) * 128 + px) * 128 + cobase;
            else
                op = (proj == 0 ? KV0 : KV2) + ((size_t)(n * 130 + yy) * 130 + (px + 1)) * 128 + cobase;
            *(unsigned*)(op)     = (unsigned)f2b(t4[0]) | ((unsigned)f2b(t4[1]) << 16);
            *(unsigned*)(op + 2) = (unsigned)f2b(t4[2]) | ((unsigned)f2b(t4[3]) << 16);
        }
    }
}

// KV border columns (x = 0 / 129) = bias
__global__ __launch_bounds__(256) void kv_border_kernel(
    unsigned short* KV0, unsigned short* KV2, const float* bkv)
{
    int idx = blockIdx.x * 256 + threadIdx.x;
    if (idx >= 16640) return;
    int cb = idx & 15;
    int t = idx >> 4;
    int col = t & 1; t >>= 1;
    int yy = t % 130; t /= 130;
    int n = t & 1;
    int buf = t >> 1;
    unsigned short* p = (buf ? KV2 : KV0)
        + ((size_t)(n * 130 + yy) * 130 + (col ? 129 : 0)) * 128 + cb * 8;
    u16x8 v;
#pragma unroll
    for (int j = 0; j < 8; ++j) v[j] = f2b(bkv[cb * 8 + j]);
    *(u16x8*)p = v;
}

// ---------------------------------------------------------------------------
// attention: both branches fused, NO LDS staging (KV is L2-resident).
// grid (2 xtile, 128 y, 2 n), block 256; thread = (x_local*4 + h):
//   wave's 64 lanes = 16 consecutive px x 4 heads -> fully coalesced Q/KV/A1p.
// ---------------------------------------------------------------------------
__global__ __launch_bounds__(256, 4) void attn_kernel(
    const unsigned short* Qb, const unsigned short* KV0,
    const unsigned short* KV2, float* pass, unsigned short* A1p)
{
    const int tid = threadIdx.x;
    const int h = tid & 3;
    const int x = blockIdx.x * 64 + (tid >> 2);
    const int y = blockIdx.y;
    const int n = blockIdx.z;
    const float SC = 0.17677669529663687f;   // 32^-0.5

    // Q (scale folded in)
    const u16x8* qp = (const u16x8*)(Qb + (((size_t)(n * 128 + y) * 128 + x) * 128) + h * 32);
    float qf[32];
#pragma unroll
    for (int d8 = 0; d8 < 4; ++d8) {
        u16x8 q8 = qp[d8];
#pragma unroll
        for (int j = 0; j < 8; ++j) qf[d8 * 8 + j] = b2f(q8[j]) * SC;
    }

    float o[32];
#pragma unroll
    for (int d = 0; d < 32; ++d) o[d] = 0.f;

#pragma unroll
    for (int b = 0; b < 2; ++b) {
        const unsigned short* kp = (b == 0 ? KV0 : KV2)
            + ((size_t)(n * 130 + y) * 130 + x) * 128 + h * 32;
        float lg[9];
#pragma unroll
        for (int t = 0; t < 9; ++t) {
            const unsigned short* wp = kp + ((t / 3) * 130 + (t % 3)) * 128;
            float s = 0.f;
#pragma unroll
            for (int d8 = 0; d8 < 4; ++d8) {
                u16x8 kk = *(const u16x8*)(wp + d8 * 8);
#pragma unroll
                for (int j = 0; j < 8; ++j) s += qf[d8 * 8 + j] * b2f(kk[j]);
            }
            lg[t] = s;
        }
        float mv = lg[0];
#pragma unroll
        for (int t = 1; t < 9; ++t) mv = fmaxf(mv, lg[t]);
        float w[9], sum = 0.f;
#pragma unroll
        for (int t = 0; t < 9; ++t) { w[t] = __expf(lg[t] - mv); sum += w[t]; }
        float r = 0.5f / sum;
#pragma unroll
        for (int t = 0; t < 9; ++t) w[t] *= r;
#pragma unroll
        for (int t = 0; t < 9; ++t) {
            const unsigned short* wp = kp + ((t / 3) * 130 + (t % 3)) * 128;
#pragma unroll
            for (int d8 = 0; d8 < 4; ++d8) {
                u16x8 kk = *(const u16x8*)(wp + d8 * 8);
#pragma unroll
                for (int j = 0; j < 8; ++j) o[d8 * 8 + j] += w[t] * b2f(kk[j]);
            }
        }
    }

    // pass: f32 NCHW
    float* pp = pass + (((size_t)(n * 128 + h * 32) * 128 + y) * 128) + x;
#pragma unroll
    for (int d = 0; d < 32; ++d) pp[(size_t)d * HW] = o[d];
    // A1p: bf16 NHWC padded (for pooling)
    unsigned short* ap = A1p + ((size_t)(n * 130 + y + 1) * 130 + (x + 1)) * 128 + h * 32;
#pragma unroll
    for (int d8 = 0; d8 < 4; ++d8) {
        u16x8 v;
#pragma unroll
        for (int j = 0; j < 8; ++j) v[j] = f2b(o[d8 * 8 + j]);
        *(u16x8*)(ap + d8 * 8) = v;
    }
}

// ---------------------------------------------------------------------------
// pool: 3x3 stride-2 conv, NHWC padded bf16 in -> f32 NCHW out (2,128,64,64)
// grid (2 co-half, 64 yo, 6 = map*2+n), block 256 (4 waves, 16 px each)
// ---------------------------------------------------------------------------
__global__ __launch_bounds__(256, 4) void pool_kernel(
    const unsigned short* G0, const unsigned short* A1, const unsigned short* G2,
    const unsigned short* Wpp, const float* bp, float* out)
{
    const int z = blockIdx.z;
    const int map = z >> 1, n = z & 1;
    const int yo = blockIdx.y;
    const int ch = blockIdx.x;
    const int tid = threadIdx.x, lane = tid & 63, l15 = lane & 15, l4 = lane >> 4, wv = tid >> 6;
    const unsigned short* In = (map == 0 ? G0 : map == 1 ? A1 : G2) + (size_t)n * 130 * 130 * 128;
    float* outp = out + (size_t)map * 1048576 + (size_t)n * 524288;

    __shared__ __align__(16) unsigned short stage[3 * 130 * 4 * 8];

    f32x4 acc[4];
#pragma unroll
    for (int a = 0; a < 4; ++a) acc[a] = (f32x4){0.f, 0.f, 0.f, 0.f};

    const int px0 = wv * 16;
    const u32x4* Ap = (const u32x4*)Wpp;

    for (int kc = 0; kc < 4; ++kc) {
        if (kc) __syncthreads();
        for (int idx = tid; idx < 1560; idx += 256) {
            int r = idx / 520;
            int rem = idx - r * 520;
            int xx = rem >> 2;
            int slot = rem & 3;
            int cd = slot ^ ((xx >> 1) & 3);
            gload16(In + ((size_t)(2 * yo + r) * 130 + xx) * 128 + kc * 32 + cd * 8,
                    stage + (size_t)(idx & ~63) * 8);
        }
        __syncthreads();
#pragma unroll
        for (int t = 0; t < 9; ++t) {
            const int ky = t / 3, kx = t % 3;
            u32x4 a[4];
#pragma unroll
            for (int mi = 0; mi < 4; ++mi)
                a[mi] = Ap[((size_t)(t * 4 + kc) * 8 + ch * 4 + mi) * 64 + lane];
            int xx = 2 * (px0 + l15) + kx;
            int slot = l4 ^ ((xx >> 1) & 3);
            bf16x8 bv = *(const bf16x8*)(stage + ((size_t)(ky * 130 + xx) * 4 + slot) * 8);
#pragma unroll
            for (int mi = 0; mi < 4; ++mi)
                acc[mi] = __builtin_amdgcn_mfma_f32_16x16x32_bf16(
                    __builtin_bit_cast(bf16x8, a[mi]), bv, acc[mi], 0, 0, 0);
        }
    }
#pragma unroll
    for (int mi = 0; mi < 4; ++mi) {
        int cobase = (ch * 4 + mi) * 16 + l4 * 4;
        int px = px0 + l15;
#pragma unroll
        for (int r = 0; r < 4; ++r) {
            int co = cobase + r;
            outp[((size_t)co * 64 + yo) * 64 + px] = acc[mi][r] + bp[co];
        }
    }
}

// ---------------------------------------------------------------------------
extern "C" void kernel_launch(void* const* d_in, const int* in_sizes, int n_in,
                              void* d_out, int out_size, void* d_ws, size_t ws_size,
                              hipStream_t stream)
{
    const float* x0 = (const float*)d_in[0];
    const float* x1 = (const float*)d_in[1];
    const float* x2 = (const float*)d_in[2];
    const float* gamma0 = (const float*)d_in[3];
    const float* beta0  = (const float*)d_in[4];
    const float* mean0  = (const float*)d_in[5];
    const float* var0   = (const float*)d_in[6];
    const float* gamma1 = (const float*)d_in[7];
    const float* beta1  = (const float*)d_in[8];
    const float* mean1  = (const float*)d_in[9];
    const float* var1   = (const float*)d_in[10];
    const float* W_adj  = (const float*)d_in[11];
    const float* b_adj  = (const float*)d_in[12];
    const float* W_conv0 = (const float*)d_in[13];
    const float* b_conv0 = (const float*)d_in[14];
    const float* W_conv1 = (const float*)d_in[15];
    const float* b_conv1 = (const float*)d_in[16];
    const float* Wq  = (const float*)d_in[17];
    const float* bq  = (const float*)d_in[18];
    const float* Wkv = (const float*)d_in[19];
    const float* bkv = (const float*)d_in[20];
    const float* W_pool = (const float*)d_in[21];
    const float* b_pool = (const float*)d_in[22];

    float* out  = (float*)d_out;
    float* pass = out + 3145728;                 // (2,128,128,128) f32 NCHW

    char* wsb = (char*)d_ws;
    const size_t FSZ = 8652800;                  // 2*130*130*128*2 B
    const size_t XSZ = 4326400;                  // 2*130*130*64*2 B
    unsigned short* F0 = (unsigned short*)(wsb);
    unsigned short* F1 = (unsigned short*)(wsb + FSZ);
    unsigned short* F2 = (unsigned short*)(wsb + 2 * FSZ);
    unsigned short* G0 = (unsigned short*)(wsb + 3 * FSZ);
    unsigned short* G1 = (unsigned short*)(wsb + 4 * FSZ);
    unsigned short* G2 = (unsigned short*)(wsb + 5 * FSZ);
    unsigned short* X0 = (unsigned short*)(wsb + 6 * FSZ);
    unsigned short* X1 = (unsigned short*)(wsb + 6 * FSZ + XSZ);
    unsigned short* X2 = (unsigned short*)(wsb + 6 * FSZ + 2 * XSZ);
    char* WAR = wsb + 6 * FSZ + 3 * XSZ;
    unsigned short* W0p    = (unsigned short*)(WAR);
    unsigned short* W1p    = (unsigned short*)(WAR + 163840);
    unsigned short* Wqp    = (unsigned short*)(WAR + 491520);
    unsigned short* Wkvp   = (unsigned short*)(WAR + 524288);
    unsigned short* Wpoolp = (unsigned short*)(WAR + 557056);
    float* b0sum = (float*)(WAR + 851968);
    float* s1a   = (float*)(WAR + 852480);
    float* t1a   = (float*)(WAR + 852992);
    // aliases (lifetimes disjoint, stream-ordered)
    unsigned short* KV0 = F0;
    unsigned short* KV2 = F1;
    unsigned short* Qb  = F2;
    unsigned short* A1p = X0;   // spans X0+X1

    zero_borders_kernel<<<dim3(65, 1, 9), 256, 0, stream>>>(X0, X1, X2, F0, F1, F2, G0, G1, G2);
    pack_kernel<<<dim3(80, 1, 6), 256, 0, stream>>>(
        W_conv0, W_adj, W_conv1, Wq, Wkv, W_pool, b_conv0, b_adj,
        gamma1, beta1, mean1, var1, W0p, W1p, Wqp, Wkvp, Wpoolp, b0sum, s1a, t1a);
    prep_kernel<<<dim3(128, 6), 256, 0, stream>>>(
        x0, x1, x2, gamma0, beta0, mean0, var0, X0, X1, X2);

    conv3_kernel<64, 0><<<dim3(2, 128, 6), 256, 0, stream>>>(
        X0, X1, X2, W0p, b0sum, s1a, t1a, F0, F1, F2);
    conv3_kernel<128, 1><<<dim3(2, 128, 6), 256, 0, stream>>>(
        F0, F1, F2, W1p, b_conv1, nullptr, nullptr, G0, G1, G2);

    zero_one_kernel<<<dim3(65), 256, 0, stream>>>(A1p);
    proj_kernel<<<dim3(2, 130, 6), 256, 0, stream>>>(
        G0, G1, G2, Wqp, Wkvp, bq, bkv, KV0, KV2, Qb);
    kv_border_kernel<<<dim3(65), 256, 0, stream>>>(KV0, KV2, bkv);

    attn_kernel<<<dim3(2, 128, 2), 256, 0, stream>>>(Qb, KV0, KV2, pass, A1p);

    pool_kernel<<<dim3(2, 64, 6), 256, 0, stream>>>(G0, A1p, G2, Wpoolp, b_pool, out);
}

// Round 4
// 328.017 us; speedup vs baseline: 6.0238x; 1.2198x over previous
//
#include <hip/hip_runtime.h>
#include <cstdint>
#include <cstddef>

// ---------------------------------------------------------------------------
// Types / helpers
// ---------------------------------------------------------------------------
typedef __bf16 bf16x8 __attribute__((ext_vector_type(8)));
typedef float f32x4 __attribute__((ext_vector_type(4)));
typedef unsigned short u16x8 __attribute__((ext_vector_type(8)));
typedef unsigned int u32x4 __attribute__((ext_vector_type(4)));

#define AS1 __attribute__((address_space(1)))
#define AS3 __attribute__((address_space(3)))

__device__ __forceinline__ void gload16(const void* g, void* l) {
    // async global->LDS, 16B per lane; LDS dest = wave-uniform base + lane*16
    __builtin_amdgcn_global_load_lds((AS1 unsigned int*)(unsigned long long)g,
                                     (AS3 unsigned int*)l, 16, 0, 0);
}

__device__ __forceinline__ unsigned short f2b(float f) {  // f32 -> bf16 RNE
    unsigned u = __builtin_bit_cast(unsigned, f);
    return (unsigned short)((u + 0x7fffu + ((u >> 16) & 1u)) >> 16);
}
__device__ __forceinline__ float b2f(unsigned short h) {
    return __builtin_bit_cast(float, ((unsigned)h) << 16);
}

static constexpr int HW = 16384;

// ---------------------------------------------------------------------------
// zero borders of 9 padded NHWC buffers (X*: C=64, F*/G*: C=128)
// ---------------------------------------------------------------------------
__global__ __launch_bounds__(256) void zero_borders_kernel(
    unsigned short* X0, unsigned short* X1, unsigned short* X2,
    unsigned short* F0, unsigned short* F1, unsigned short* F2,
    unsigned short* G0, unsigned short* G1, unsigned short* G2)
{
    int z = blockIdx.z;
    unsigned short* p; int C;
    switch (z) {
        case 0: p = X0; C = 64; break;
        case 1: p = X1; C = 64; break;
        case 2: p = X2; C = 64; break;
        case 3: p = F0; C = 128; break;
        case 4: p = F1; C = 128; break;
        case 5: p = F2; C = 128; break;
        case 6: p = G0; C = 128; break;
        case 7: p = G1; C = 128; break;
        default: p = G2; C = 128; break;
    }
    int chunks = C >> 3;
    int total = 2 * 516 * chunks;
    int idx = blockIdx.x * 256 + threadIdx.x;
    if (idx >= total) return;
    int cb = idx % chunks;
    int pidx = idx / chunks;
    int n = pidx / 516;
    int b = pidx % 516;
    int y, x;
    if (b < 130)      { y = 0;       x = b; }
    else if (b < 260) { y = 129;     x = b - 130; }
    else if (b < 388) { y = b - 259; x = 0; }
    else              { y = b - 387; x = 129; }
    u32x4 zz = {0u, 0u, 0u, 0u};
    *(u32x4*)(p + ((size_t)((n * 130 + y) * 130 + x)) * C + cb * 8) = zz;
}

// zero borders of one C=128 padded buffer (A1p, after X region is dead)
__global__ __launch_bounds__(256) void zero_one_kernel(unsigned short* p)
{
    int idx = blockIdx.x * 256 + threadIdx.x;
    if (idx >= 2 * 516 * 16) return;
    int cb = idx & 15;
    int pidx = idx >> 4;
    int n = pidx / 516;
    int b = pidx % 516;
    int y, x;
    if (b < 130)      { y = 0;       x = b; }
    else if (b < 260) { y = 129;     x = b - 130; }
    else if (b < 388) { y = b - 259; x = 0; }
    else              { y = b - 387; x = 129; }
    u32x4 zz = {0u, 0u, 0u, 0u};
    *(u32x4*)(p + ((size_t)((n * 130 + y) * 130 + x)) * 128 + cb * 8) = zz;
}

// ---------------------------------------------------------------------------
// pack weights into MFMA A-fragment order: [tap][kc][m][lane][8 bf16]
//   lane l of fragment (m): co = m*16 + (l&15), ci = kc*32 + (l>>4)*8 + j
// z: 0=W0p(conv0+adj tap), 1=W1p(conv1+identity tap), 2=Wqp, 3=Wkvp, 4=Wpoolp,
//    5=bias precompute (b0sum, s1, t1)
// ---------------------------------------------------------------------------
__global__ __launch_bounds__(256) void pack_kernel(
    const float* Wc0, const float* Wadj, const float* Wc1,
    const float* Wq, const float* Wkv, const float* Wpool,
    const float* bc0, const float* badj,
    const float* g1, const float* be1, const float* m1, const float* v1,
    unsigned short* W0p, unsigned short* W1p, unsigned short* Wqp,
    unsigned short* Wkvp, unsigned short* Wpp,
    float* b0sum, float* s1a, float* t1a)
{
    int z = blockIdx.z;
    int idx = blockIdx.x * 256 + threadIdx.x;
    if (z == 5) {
        if (idx < 128) {
            int co = idx;
            b0sum[co] = bc0[co] + badj[co];
            float s = g1[co] * rsqrtf(v1[co] + 1e-5f);
            s1a[co] = s;
            t1a[co] = be1[co] - m1[co] * s;
        }
        return;
    }
    int CIN, NTAP; unsigned short* dst;
    switch (z) {
        case 0: CIN = 64;  NTAP = 10; dst = W0p;  break;
        case 1: CIN = 128; NTAP = 10; dst = W1p;  break;
        case 2: CIN = 128; NTAP = 1;  dst = Wqp;  break;
        case 3: CIN = 128; NTAP = 1;  dst = Wkvp; break;
        default: CIN = 128; NTAP = 9; dst = Wpp;  break;
    }
    int KCN = CIN / 32;
    int count = NTAP * KCN * 512;
    if (idx >= count) return;
    int lane = idx & 63;
    int m = (idx >> 6) & 7;
    int rest = idx >> 9;
    int kc = rest % KCN;
    int tap = rest / KCN;
    int co = m * 16 + (lane & 15);
    int cib = kc * 32 + ((lane >> 4) << 3);
    unsigned short vals[8];
#pragma unroll
    for (int j = 0; j < 8; ++j) {
        int ci = cib + j;
        float v;
        if (z == 0)       v = (tap < 9) ? Wc0[((size_t)co * 64 + ci) * 9 + tap] : Wadj[co * 64 + ci];
        else if (z == 1)  v = (tap < 9) ? Wc1[((size_t)co * 128 + ci) * 9 + tap] : (co == ci ? 1.0f : 0.0f);
        else if (z == 2)  v = Wq[co * 128 + ci];
        else if (z == 3)  v = Wkv[co * 128 + ci];
        else              v = Wpool[((size_t)co * 128 + ci) * 9 + tap];
        vals[j] = f2b(v);
    }
    u32x4 pk;
    pk.x = vals[0] | ((unsigned)vals[1] << 16);
    pk.y = vals[2] | ((unsigned)vals[3] << 16);
    pk.z = vals[4] | ((unsigned)vals[5] << 16);
    pk.w = vals[6] | ((unsigned)vals[7] << 16);
    *(u32x4*)(dst + (size_t)idx * 8) = pk;
}

// ---------------------------------------------------------------------------
// prep: BN0 + pad + NCHW f32 -> NHWC bf16 padded (2,130,130,64), interior only
// grid (128 y, 6 = map*2+n), block 256
// ---------------------------------------------------------------------------
__global__ __launch_bounds__(256) void prep_kernel(
    const float* x0, const float* x1, const float* x2,
    const float* g0, const float* be0, const float* me0, const float* va0,
    unsigned short* X0, unsigned short* X1, unsigned short* X2)
{
    const int y = blockIdx.x;
    const int mz = blockIdx.y;
    const int map = mz >> 1, n = mz & 1;
    const float* in = (map == 0 ? x0 : map == 1 ? x1 : x2) + (size_t)n * 64 * HW + y * 128;
    unsigned short* out = (map == 0 ? X0 : map == 1 ? X1 : X2)
                          + ((size_t)(n * 130 + y + 1) * 130 + 1) * 64;
    const int x = threadIdx.x & 127;
    for (int cb = threadIdx.x >> 7; cb < 8; cb += 2) {
        unsigned short vals[8];
#pragma unroll
        for (int j = 0; j < 8; ++j) {
            int ci = cb * 8 + j;
            float s = g0[ci] * rsqrtf(va0[ci] + 1e-5f);
            float t = be0[ci] - me0[ci] * s;
            vals[j] = f2b(in[(size_t)ci * HW + x] * s + t);
        }
        u32x4 pk;
        pk.x = vals[0] | ((unsigned)vals[1] << 16);
        pk.y = vals[2] | ((unsigned)vals[3] << 16);
        pk.z = vals[4] | ((unsigned)vals[5] << 16);
        pk.w = vals[6] | ((unsigned)vals[7] << 16);
        *(u32x4*)(out + (size_t)x * 64 + cb * 8) = pk;
    }
}

// ---------------------------------------------------------------------------
// conv3: 3x3 conv (+residual tap) as implicit GEMM, NHWC padded in/out.
// EPI 0: F = bn1(lrelu(acc + b0sum))   EPI 1: G = lrelu(acc + bconv1)
// grid (2 co-half, 128 y, 6 = map*2+n), block 256 (4 waves, wave = 32 px)
// ---------------------------------------------------------------------------
template <int CIN, int EPI>
__global__ __launch_bounds__(256, 4) void conv3_kernel(
    const unsigned short* I0, const unsigned short* I1, const unsigned short* I2,
    const unsigned short* Wp, const float* bA, const float* bB, const float* bC,
    unsigned short* O0, unsigned short* O1, unsigned short* O2)
{
    constexpr int KCN = CIN / 32;
    constexpr int TKY[10] = {0,0,0,1,1,1,2,2,2,1};
    constexpr int TKX[10] = {0,1,2,0,1,2,0,1,2,1};
    const int tid = threadIdx.x;
    const int lane = tid & 63;
    const int l15 = lane & 15, l4 = lane >> 4;
    const int wv = tid >> 6;
    const int ch = blockIdx.x;
    const int y = blockIdx.y;
    const int mz = blockIdx.z;
    const int map = mz >> 1, n = mz & 1;
    const unsigned short* In = (map == 0 ? I0 : map == 1 ? I1 : I2) + (size_t)n * 130 * 130 * CIN;
    unsigned short* On = (map == 0 ? O0 : map == 1 ? O1 : O2) + (size_t)n * 130 * 130 * 128;

    __shared__ __align__(16) unsigned short stage[3 * 130 * 4 * 8];  // 24,960 B

    f32x4 acc[4][2];
#pragma unroll
    for (int a = 0; a < 4; ++a)
#pragma unroll
        for (int b = 0; b < 2; ++b) acc[a][b] = (f32x4){0.f, 0.f, 0.f, 0.f};

    const int px0 = wv * 32;
    const u32x4* Ap = (const u32x4*)Wp;

    for (int kc = 0; kc < KCN; ++kc) {
        if (kc) __syncthreads();
        // stage 3 rows x 130 x 32ci bf16, source pre-swizzled so ds_read is ~conflict-free
        for (int idx = tid; idx < 1560; idx += 256) {
            int r = idx / 520;
            int rem = idx - r * 520;
            int xx = rem >> 2;
            int slot = rem & 3;
            int cd = slot ^ ((xx >> 1) & 3);
            const unsigned short* src = In + ((size_t)(y + r) * 130 + xx) * CIN + kc * 32 + cd * 8;
            gload16(src, stage + (size_t)(idx & ~63) * 8);
        }
        __syncthreads();
#pragma unroll
        for (int t = 0; t < 10; ++t) {
            const int ky = TKY[t], kx = TKX[t];
            u32x4 a[4];
#pragma unroll
            for (int mi = 0; mi < 4; ++mi)
                a[mi] = Ap[((size_t)(t * KCN + kc) * 8 + ch * 4 + mi) * 64 + lane];
            bf16x8 bv[2];
#pragma unroll
            for (int nf = 0; nf < 2; ++nf) {
                int xx = px0 + nf * 16 + l15 + kx;
                int slot = l4 ^ ((xx >> 1) & 3);
                bv[nf] = *(const bf16x8*)(stage + ((size_t)(ky * 130 + xx) * 4 + slot) * 8);
            }
#pragma unroll
            for (int mi = 0; mi < 4; ++mi) {
                bf16x8 av = __builtin_bit_cast(bf16x8, a[mi]);
#pragma unroll
                for (int nf = 0; nf < 2; ++nf)
                    acc[mi][nf] = __builtin_amdgcn_mfma_f32_16x16x32_bf16(av, bv[nf], acc[mi][nf], 0, 0, 0);
            }
        }
    }
    // epilogue: bias + lrelu (+ BN1 fold for EPI 0), store NHWC bf16 interior
#pragma unroll
    for (int mi = 0; mi < 4; ++mi) {
#pragma unroll
        for (int nf = 0; nf < 2; ++nf) {
            int px = px0 + nf * 16 + l15;
            int cobase = (ch * 4 + mi) * 16 + l4 * 4;
            float t4[4];
#pragma unroll
            for (int r = 0; r < 4; ++r) {
                int co = cobase + r;
                float v = acc[mi][nf][r] + bA[co];
                v = v > 0.f ? v : 0.05f * v;
                if (EPI == 0) v = v * bB[co] + bC[co];
                t4[r] = v;
            }
            unsigned short* op = On + ((size_t)(y + 1) * 130 + (px + 1)) * 128 + cobase;
            *(unsigned*)(op)     = (unsigned)f2b(t4[0]) | ((unsigned)f2b(t4[1]) << 16);
            *(unsigned*)(op + 2) = (unsigned)f2b(t4[2]) | ((unsigned)f2b(t4[3]) << 16);
        }
    }
}

// ---------------------------------------------------------------------------
// proj: 1x1 conv GEMM. z: 0 = G0->KV0 (rows 0..129), 1 = G2->KV2, 2 = G1->Qb
// grid (2 co-half, 130 yy, 6 = proj*2+n), block 256
// ---------------------------------------------------------------------------
__global__ __launch_bounds__(256, 4) void proj_kernel(
    const unsigned short* G0, const unsigned short* G1, const unsigned short* G2,
    const unsigned short* Wqp, const unsigned short* Wkvp,
    const float* bq, const float* bkv,
    unsigned short* KV0, unsigned short* KV2, unsigned short* Qb)
{
    const int z = blockIdx.z;
    const int proj = z >> 1, n = z & 1;
    const int yy = blockIdx.y;
    if (proj == 2 && (yy == 0 || yy == 129)) return;
    const int tid = threadIdx.x;
    const int lane = tid & 63, l15 = lane & 15, l4 = lane >> 4, wv = tid >> 6;
    const int ch = blockIdx.x;
    const unsigned short* In = (proj == 0 ? G0 : proj == 1 ? G2 : G1) + (size_t)n * 130 * 130 * 128;
    const unsigned short* Wp = (proj == 2) ? Wqp : Wkvp;
    const float* bias = (proj == 2) ? bq : bkv;

    __shared__ __align__(16) unsigned short stage[130 * 4 * 8];

    f32x4 acc[4][2];
#pragma unroll
    for (int a = 0; a < 4; ++a)
#pragma unroll
        for (int b = 0; b < 2; ++b) acc[a][b] = (f32x4){0.f, 0.f, 0.f, 0.f};

    const int px0 = wv * 32;
    const u32x4* Ap = (const u32x4*)Wp;

    for (int kc = 0; kc < 4; ++kc) {
        if (kc) __syncthreads();
        for (int idx = tid; idx < 520; idx += 256) {
            int xx = idx >> 2, slot = idx & 3;
            int cd = slot ^ ((xx >> 1) & 3);
            gload16(In + ((size_t)yy * 130 + xx) * 128 + kc * 32 + cd * 8,
                    stage + (size_t)(idx & ~63) * 8);
        }
        __syncthreads();
        u32x4 a[4];
#pragma unroll
        for (int mi = 0; mi < 4; ++mi)
            a[mi] = Ap[((size_t)kc * 8 + ch * 4 + mi) * 64 + lane];
        bf16x8 bv[2];
#pragma unroll
        for (int nf = 0; nf < 2; ++nf) {
            int xx = px0 + nf * 16 + l15 + 1;
            int slot = l4 ^ ((xx >> 1) & 3);
            bv[nf] = *(const bf16x8*)(stage + ((size_t)xx * 4 + slot) * 8);
        }
#pragma unroll
        for (int mi = 0; mi < 4; ++mi) {
            bf16x8 av = __builtin_bit_cast(bf16x8, a[mi]);
#pragma unroll
            for (int nf = 0; nf < 2; ++nf)
                acc[mi][nf] = __builtin_amdgcn_mfma_f32_16x16x32_bf16(av, bv[nf], acc[mi][nf], 0, 0, 0);
        }
        if (kc < 3) __syncthreads();
    }
#pragma unroll
    for (int mi = 0; mi < 4; ++mi) {
#pragma unroll
        for (int nf = 0; nf < 2; ++nf) {
            int px = px0 + nf * 16 + l15;
            int cobase = (ch * 4 + mi) * 16 + l4 * 4;
            float t4[4];
#pragma unroll
            for (int r = 0; r < 4; ++r) t4[r] = acc[mi][nf][r] + bias[cobase + r];
            unsigned short* op;
            if (proj == 2)
                op = Qb + ((size_t)(n * 128 + yy - 1) * 128 + px) * 128 + cobase;
            else
                op = (proj == 0 ? KV0 : KV2) + ((size_t)(n * 130 + yy) * 130 + (px + 1)) * 128 + cobase;
            *(unsigned*)(op)     = (unsigned)f2b(t4[0]) | ((unsigned)f2b(t4[1]) << 16);
            *(unsigned*)(op + 2) = (unsigned)f2b(t4[2]) | ((unsigned)f2b(t4[3]) << 16);
        }
    }
}

// KV border columns (x = 0 / 129) = bias
__global__ __launch_bounds__(256) void kv_border_kernel(
    unsigned short* KV0, unsigned short* KV2, const float* bkv)
{
    int idx = blockIdx.x * 256 + threadIdx.x;
    if (idx >= 16640) return;
    int cb = idx & 15;
    int t = idx >> 4;
    int col = t & 1; t >>= 1;
    int yy = t % 130; t /= 130;
    int n = t & 1;
    int buf = t >> 1;
    unsigned short* p = (buf ? KV2 : KV0)
        + ((size_t)(n * 130 + yy) * 130 + (col ? 129 : 0)) * 128 + cb * 8;
    u16x8 v;
#pragma unroll
    for (int j = 0; j < 8; ++j) v[j] = f2b(bkv[cb * 8 + j]);
    *(u16x8*)p = v;
}

// ---------------------------------------------------------------------------
// attention: both branches fused, no LDS staging for KV (L2-chunked by XCD
// swizzle); pass written as full 128-B lines via LDS transpose.
// 1-D grid 512 blocks; work = (bid&7)*64 + (bid>>3)  (XCD-contiguous chunks:
// each XCD covers 32 consecutive y rows of one n -> KV set ~2.3MB fits 4MB L2)
// block 256: thread = (xl*4 + h); wave = 16 px x 4 heads (coalesced).
// ---------------------------------------------------------------------------
__global__ __launch_bounds__(256, 2) void attn_kernel(
    const unsigned short* Qb, const unsigned short* KV0,
    const unsigned short* KV2, float* pass, unsigned short* A1p)
{
    const int bid = blockIdx.x;
    const int work = (bid & 7) * 64 + (bid >> 3);
    const int n = work >> 8;
    const int rr = work & 255;
    const int y = rr >> 1;
    const int x0 = (rr & 1) * 64;
    const int tid = threadIdx.x;
    const int h = tid & 3;
    const int xl = tid >> 2;
    const int x = x0 + xl;
    const float SC = 0.17677669529663687f;   // 32^-0.5

    __shared__ float lds[64][133];

    // Q (scale folded in)
    const u16x8* qp = (const u16x8*)(Qb + (((size_t)(n * 128 + y) * 128 + x) * 128) + h * 32);
    float qf[32];
#pragma unroll
    for (int d8 = 0; d8 < 4; ++d8) {
        u16x8 q8 = qp[d8];
#pragma unroll
        for (int j = 0; j < 8; ++j) qf[d8 * 8 + j] = b2f(q8[j]) * SC;
    }

    float o[32];
#pragma unroll
    for (int d = 0; d < 32; ++d) o[d] = 0.f;

#pragma unroll
    for (int b = 0; b < 2; ++b) {
        const unsigned short* kp = (b == 0 ? KV0 : KV2)
            + ((size_t)(n * 130 + y) * 130 + x) * 128 + h * 32;
        float lg[9];
#pragma unroll
        for (int t = 0; t < 9; ++t) {
            const unsigned short* wp = kp + ((t / 3) * 130 + (t % 3)) * 128;
            float s = 0.f;
#pragma unroll
            for (int d8 = 0; d8 < 4; ++d8) {
                u16x8 kk = *(const u16x8*)(wp + d8 * 8);
#pragma unroll
                for (int j = 0; j < 8; ++j) s += qf[d8 * 8 + j] * b2f(kk[j]);
            }
            lg[t] = s;
        }
        float mv = lg[0];
#pragma unroll
        for (int t = 1; t < 9; ++t) mv = fmaxf(mv, lg[t]);
        float w[9], sum = 0.f;
#pragma unroll
        for (int t = 0; t < 9; ++t) { w[t] = __expf(lg[t] - mv); sum += w[t]; }
        float r = 0.5f / sum;
#pragma unroll
        for (int t = 0; t < 9; ++t) w[t] *= r;
#pragma unroll
        for (int t = 0; t < 9; ++t) {
            const unsigned short* wp = kp + ((t / 3) * 130 + (t % 3)) * 128;
#pragma unroll
            for (int d8 = 0; d8 < 4; ++d8) {
                u16x8 kk = *(const u16x8*)(wp + d8 * 8);
#pragma unroll
                for (int j = 0; j < 8; ++j) o[d8 * 8 + j] += w[t] * b2f(kk[j]);
            }
        }
    }

    // A1p: bf16 NHWC padded (for pooling) -- direct from registers
    unsigned short* ap = A1p + ((size_t)(n * 130 + y + 1) * 130 + (x + 1)) * 128 + h * 32;
#pragma unroll
    for (int d8 = 0; d8 < 4; ++d8) {
        u16x8 v;
#pragma unroll
        for (int j = 0; j < 8; ++j) v[j] = f2b(o[d8 * 8 + j]);
        *(u16x8*)(ap + d8 * 8) = v;
    }

    // stage to LDS for transposed full-line pass writes
#pragma unroll
    for (int d = 0; d < 32; ++d) lds[xl][h * 32 + d] = o[d];
    __syncthreads();

    // pass: f32 NCHW, each store = 16 lanes x 16B = 256 B contiguous per plane
    const int lane = tid & 63, wvv = tid >> 6;
    const int xs = (lane & 15) * 4;
#pragma unroll
    for (int it = 0; it < 8; ++it) {
        int c = wvv * 32 + it * 4 + (lane >> 4);
        f32x4 v = { lds[xs + 0][c], lds[xs + 1][c], lds[xs + 2][c], lds[xs + 3][c] };
        *(f32x4*)(pass + ((size_t)(n * 128 + c) * HW) + y * 128 + x0 + xs) = v;
    }
}

// ---------------------------------------------------------------------------
// pool: 3x3 stride-2 conv, NHWC padded bf16 in -> f32 NCHW out (2,128,64,64)
// grid (2 co-half, 64 yo, 6 = map*2+n), block 256 (4 waves, 16 px each)
// ---------------------------------------------------------------------------
__global__ __launch_bounds__(256, 4) void pool_kernel(
    const unsigned short* G0, const unsigned short* A1, const unsigned short* G2,
    const unsigned short* Wpp, const float* bp, float* out)
{
    const int z = blockIdx.z;
    const int map = z >> 1, n = z & 1;
    const int yo = blockIdx.y;
    const int ch = blockIdx.x;
    const int tid = threadIdx.x, lane = tid & 63, l15 = lane & 15, l4 = lane >> 4, wv = tid >> 6;
    const unsigned short* In = (map == 0 ? G0 : map == 1 ? A1 : G2) + (size_t)n * 130 * 130 * 128;
    float* outp = out + (size_t)map * 1048576 + (size_t)n * 524288;

    __shared__ __align__(16) unsigned short stage[3 * 130 * 4 * 8];

    f32x4 acc[4];
#pragma unroll
    for (int a = 0; a < 4; ++a) acc[a] = (f32x4){0.f, 0.f, 0.f, 0.f};

    const int px0 = wv * 16;
    const u32x4* Ap = (const u32x4*)Wpp;

    for (int kc = 0; kc < 4; ++kc) {
        if (kc) __syncthreads();
        for (int idx = tid; idx < 1560; idx += 256) {
            int r = idx / 520;
            int rem = idx - r * 520;
            int xx = rem >> 2;
            int slot = rem & 3;
            int cd = slot ^ ((xx >> 1) & 3);
            gload16(In + ((size_t)(2 * yo + r) * 130 + xx) * 128 + kc * 32 + cd * 8,
                    stage + (size_t)(idx & ~63) * 8);
        }
        __syncthreads();
#pragma unroll
        for (int t = 0; t < 9; ++t) {
            const int ky = t / 3, kx = t % 3;
            u32x4 a[4];
#pragma unroll
            for (int mi = 0; mi < 4; ++mi)
                a[mi] = Ap[((size_t)(t * 4 + kc) * 8 + ch * 4 + mi) * 64 + lane];
            int xx = 2 * (px0 + l15) + kx;
            int slot = l4 ^ ((xx >> 1) & 3);
            bf16x8 bv = *(const bf16x8*)(stage + ((size_t)(ky * 130 + xx) * 4 + slot) * 8);
#pragma unroll
            for (int mi = 0; mi < 4; ++mi)
                acc[mi] = __builtin_amdgcn_mfma_f32_16x16x32_bf16(
                    __builtin_bit_cast(bf16x8, a[mi]), bv, acc[mi], 0, 0, 0);
        }
    }
#pragma unroll
    for (int mi = 0; mi < 4; ++mi) {
        int cobase = (ch * 4 + mi) * 16 + l4 * 4;
        int px = px0 + l15;
#pragma unroll
        for (int r = 0; r < 4; ++r) {
            int co = cobase + r;
            outp[((size_t)co * 64 + yo) * 64 + px] = acc[mi][r] + bp[co];
        }
    }
}

// ---------------------------------------------------------------------------
extern "C" void kernel_launch(void* const* d_in, const int* in_sizes, int n_in,
                              void* d_out, int out_size, void* d_ws, size_t ws_size,
                              hipStream_t stream)
{
    const float* x0 = (const float*)d_in[0];
    const float* x1 = (const float*)d_in[1];
    const float* x2 = (const float*)d_in[2];
    const float* gamma0 = (const float*)d_in[3];
    const float* beta0  = (const float*)d_in[4];
    const float* mean0  = (const float*)d_in[5];
    const float* var0   = (const float*)d_in[6];
    const float* gamma1 = (const float*)d_in[7];
    const float* beta1  = (const float*)d_in[8];
    const float* mean1  = (const float*)d_in[9];
    const float* var1   = (const float*)d_in[10];
    const float* W_adj  = (const float*)d_in[11];
    const float* b_adj  = (const float*)d_in[12];
    const float* W_conv0 = (const float*)d_in[13];
    const float* b_conv0 = (const float*)d_in[14];
    const float* W_conv1 = (const float*)d_in[15];
    const float* b_conv1 = (const float*)d_in[16];
    const float* Wq  = (const float*)d_in[17];
    const float* bq  = (const float*)d_in[18];
    const float* Wkv = (const float*)d_in[19];
    const float* bkv = (const float*)d_in[20];
    const float* W_pool = (const float*)d_in[21];
    const float* b_pool = (const float*)d_in[22];

    float* out  = (float*)d_out;
    float* pass = out + 3145728;                 // (2,128,128,128) f32 NCHW

    char* wsb = (char*)d_ws;
    const size_t FSZ = 8652800;                  // 2*130*130*128*2 B
    const size_t XSZ = 4326400;                  // 2*130*130*64*2 B
    unsigned short* F0 = (unsigned short*)(wsb);
    unsigned short* F1 = (unsigned short*)(wsb + FSZ);
    unsigned short* F2 = (unsigned short*)(wsb + 2 * FSZ);
    unsigned short* G0 = (unsigned short*)(wsb + 3 * FSZ);
    unsigned short* G1 = (unsigned short*)(wsb + 4 * FSZ);
    unsigned short* G2 = (unsigned short*)(wsb + 5 * FSZ);
    unsigned short* X0 = (unsigned short*)(wsb + 6 * FSZ);
    unsigned short* X1 = (unsigned short*)(wsb + 6 * FSZ + XSZ);
    unsigned short* X2 = (unsigned short*)(wsb + 6 * FSZ + 2 * XSZ);
    char* WAR = wsb + 6 * FSZ + 3 * XSZ;
    unsigned short* W0p    = (unsigned short*)(WAR);
    unsigned short* W1p    = (unsigned short*)(WAR + 163840);
    unsigned short* Wqp    = (unsigned short*)(WAR + 491520);
    unsigned short* Wkvp   = (unsigned short*)(WAR + 524288);
    unsigned short* Wpoolp = (unsigned short*)(WAR + 557056);
    float* b0sum = (float*)(WAR + 851968);
    float* s1a   = (float*)(WAR + 852480);
    float* t1a   = (float*)(WAR + 852992);
    // aliases (lifetimes disjoint, stream-ordered)
    unsigned short* KV0 = F0;
    unsigned short* KV2 = F1;
    unsigned short* Qb  = F2;
    unsigned short* A1p = X0;   // spans X0+X1

    zero_borders_kernel<<<dim3(65, 1, 9), 256, 0, stream>>>(X0, X1, X2, F0, F1, F2, G0, G1, G2);
    pack_kernel<<<dim3(80, 1, 6), 256, 0, stream>>>(
        W_conv0, W_adj, W_conv1, Wq, Wkv, W_pool, b_conv0, b_adj,
        gamma1, beta1, mean1, var1, W0p, W1p, Wqp, Wkvp, Wpoolp, b0sum, s1a, t1a);
    prep_kernel<<<dim3(128, 6), 256, 0, stream>>>(
        x0, x1, x2, gamma0, beta0, mean0, var0, X0, X1, X2);

    conv3_kernel<64, 0><<<dim3(2, 128, 6), 256, 0, stream>>>(
        X0, X1, X2, W0p, b0sum, s1a, t1a, F0, F1, F2);
    conv3_kernel<128, 1><<<dim3(2, 128, 6), 256, 0, stream>>>(
        F0, F1, F2, W1p, b_conv1, nullptr, nullptr, G0, G1, G2);

    zero_one_kernel<<<dim3(65), 256, 0, stream>>>(A1p);
    proj_kernel<<<dim3(2, 130, 6), 256, 0, stream>>>(
        G0, G1, G2, Wqp, Wkvp, bq, bkv, KV0, KV2, Qb);
    kv_border_kernel<<<dim3(65), 256, 0, stream>>>(KV0, KV2, bkv);

    attn_kernel<<<dim3(512), 256, 0, stream>>>(Qb, KV0, KV2, pass, A1p);

    pool_kernel<<<dim3(2, 64, 6), 256, 0, stream>>>(G0, A1p, G2, Wpoolp, b_pool, out);
}

// Round 5
// 285.567 us; speedup vs baseline: 6.9192x; 1.1486x over previous
//
#include <hip/hip_runtime.h>
#include <cstdint>
#include <cstddef>

// ---------------------------------------------------------------------------
// Types / helpers
// ---------------------------------------------------------------------------
typedef __bf16 bf16x8 __attribute__((ext_vector_type(8)));
typedef float f32x4 __attribute__((ext_vector_type(4)));
typedef unsigned short u16x8 __attribute__((ext_vector_type(8)));
typedef unsigned int u32x4 __attribute__((ext_vector_type(4)));

#define AS1 __attribute__((address_space(1)))
#define AS3 __attribute__((address_space(3)))

__device__ __forceinline__ void gload16(const void* g, void* l) {
    // async global->LDS, 16B per lane; LDS dest = wave-uniform base + lane*16
    __builtin_amdgcn_global_load_lds((AS1 unsigned int*)(unsigned long long)g,
                                     (AS3 unsigned int*)l, 16, 0, 0);
}

__device__ __forceinline__ unsigned short f2b(float f) {  // f32 -> bf16 RNE
    unsigned u = __builtin_bit_cast(unsigned, f);
    return (unsigned short)((u + 0x7fffu + ((u >> 16) & 1u)) >> 16);
}
__device__ __forceinline__ float b2f(unsigned short h) {
    return __builtin_bit_cast(float, ((unsigned)h) << 16);
}

static constexpr int HW = 16384;

// ---------------------------------------------------------------------------
// zero borders of 9 padded NHWC buffers (X*: C=64, F*/G*: C=128)
// ---------------------------------------------------------------------------
__global__ __launch_bounds__(256) void zero_borders_kernel(
    unsigned short* X0, unsigned short* X1, unsigned short* X2,
    unsigned short* F0, unsigned short* F1, unsigned short* F2,
    unsigned short* G0, unsigned short* G1, unsigned short* G2)
{
    int z = blockIdx.z;
    unsigned short* p; int C;
    switch (z) {
        case 0: p = X0; C = 64; break;
        case 1: p = X1; C = 64; break;
        case 2: p = X2; C = 64; break;
        case 3: p = F0; C = 128; break;
        case 4: p = F1; C = 128; break;
        case 5: p = F2; C = 128; break;
        case 6: p = G0; C = 128; break;
        case 7: p = G1; C = 128; break;
        default: p = G2; C = 128; break;
    }
    int chunks = C >> 3;
    int total = 2 * 516 * chunks;
    int idx = blockIdx.x * 256 + threadIdx.x;
    if (idx >= total) return;
    int cb = idx % chunks;
    int pidx = idx / chunks;
    int n = pidx / 516;
    int b = pidx % 516;
    int y, x;
    if (b < 130)      { y = 0;       x = b; }
    else if (b < 260) { y = 129;     x = b - 130; }
    else if (b < 388) { y = b - 259; x = 0; }
    else              { y = b - 387; x = 129; }
    u32x4 zz = {0u, 0u, 0u, 0u};
    *(u32x4*)(p + ((size_t)((n * 130 + y) * 130 + x)) * C + cb * 8) = zz;
}

// zero borders of one C=128 padded buffer (A1p, after X region is dead)
__global__ __launch_bounds__(256) void zero_one_kernel(unsigned short* p)
{
    int idx = blockIdx.x * 256 + threadIdx.x;
    if (idx >= 2 * 516 * 16) return;
    int cb = idx & 15;
    int pidx = idx >> 4;
    int n = pidx / 516;
    int b = pidx % 516;
    int y, x;
    if (b < 130)      { y = 0;       x = b; }
    else if (b < 260) { y = 129;     x = b - 130; }
    else if (b < 388) { y = b - 259; x = 0; }
    else              { y = b - 387; x = 129; }
    u32x4 zz = {0u, 0u, 0u, 0u};
    *(u32x4*)(p + ((size_t)((n * 130 + y) * 130 + x)) * 128 + cb * 8) = zz;
}

// ---------------------------------------------------------------------------
// pack weights into MFMA A-fragment order: [tap][kc][m][lane][8 bf16]
//   lane l of fragment (m): co = m*16 + (l&15), ci = kc*32 + (l>>4)*8 + j
// z: 0=W0p(conv0+adj tap), 1=W1p(conv1+identity tap), 2=Wqp, 3=Wkvp, 4=Wpoolp,
//    5=bias precompute (b0sum, s1, t1)
// ---------------------------------------------------------------------------
__global__ __launch_bounds__(256) void pack_kernel(
    const float* Wc0, const float* Wadj, const float* Wc1,
    const float* Wq, const float* Wkv, const float* Wpool,
    const float* bc0, const float* badj,
    const float* g1, const float* be1, const float* m1, const float* v1,
    unsigned short* W0p, unsigned short* W1p, unsigned short* Wqp,
    unsigned short* Wkvp, unsigned short* Wpp,
    float* b0sum, float* s1a, float* t1a)
{
    int z = blockIdx.z;
    int idx = blockIdx.x * 256 + threadIdx.x;
    if (z == 5) {
        if (idx < 128) {
            int co = idx;
            b0sum[co] = bc0[co] + badj[co];
            float s = g1[co] * rsqrtf(v1[co] + 1e-5f);
            s1a[co] = s;
            t1a[co] = be1[co] - m1[co] * s;
        }
        return;
    }
    int CIN, NTAP; unsigned short* dst;
    switch (z) {
        case 0: CIN = 64;  NTAP = 10; dst = W0p;  break;
        case 1: CIN = 128; NTAP = 10; dst = W1p;  break;
        case 2: CIN = 128; NTAP = 1;  dst = Wqp;  break;
        case 3: CIN = 128; NTAP = 1;  dst = Wkvp; break;
        default: CIN = 128; NTAP = 9; dst = Wpp;  break;
    }
    int KCN = CIN / 32;
    int count = NTAP * KCN * 512;
    if (idx >= count) return;
    int lane = idx & 63;
    int m = (idx >> 6) & 7;
    int rest = idx >> 9;
    int kc = rest % KCN;
    int tap = rest / KCN;
    int co = m * 16 + (lane & 15);
    int cib = kc * 32 + ((lane >> 4) << 3);
    unsigned short vals[8];
#pragma unroll
    for (int j = 0; j < 8; ++j) {
        int ci = cib + j;
        float v;
        if (z == 0)       v = (tap < 9) ? Wc0[((size_t)co * 64 + ci) * 9 + tap] : Wadj[co * 64 + ci];
        else if (z == 1)  v = (tap < 9) ? Wc1[((size_t)co * 128 + ci) * 9 + tap] : (co == ci ? 1.0f : 0.0f);
        else if (z == 2)  v = Wq[co * 128 + ci];
        else if (z == 3)  v = Wkv[co * 128 + ci];
        else              v = Wpool[((size_t)co * 128 + ci) * 9 + tap];
        vals[j] = f2b(v);
    }
    u32x4 pk;
    pk.x = vals[0] | ((unsigned)vals[1] << 16);
    pk.y = vals[2] | ((unsigned)vals[3] << 16);
    pk.z = vals[4] | ((unsigned)vals[5] << 16);
    pk.w = vals[6] | ((unsigned)vals[7] << 16);
    *(u32x4*)(dst + (size_t)idx * 8) = pk;
}

// ---------------------------------------------------------------------------
// prep: BN0 + pad + NCHW f32 -> NHWC bf16 padded (2,130,130,64), interior only
// grid (128 y, 6 = map*2+n), block 256
// ---------------------------------------------------------------------------
__global__ __launch_bounds__(256) void prep_kernel(
    const float* x0, const float* x1, const float* x2,
    const float* g0, const float* be0, const float* me0, const float* va0,
    unsigned short* X0, unsigned short* X1, unsigned short* X2)
{
    const int y = blockIdx.x;
    const int mz = blockIdx.y;
    const int map = mz >> 1, n = mz & 1;
    const float* in = (map == 0 ? x0 : map == 1 ? x1 : x2) + (size_t)n * 64 * HW + y * 128;
    unsigned short* out = (map == 0 ? X0 : map == 1 ? X1 : X2)
                          + ((size_t)(n * 130 + y + 1) * 130 + 1) * 64;
    const int x = threadIdx.x & 127;
    for (int cb = threadIdx.x >> 7; cb < 8; cb += 2) {
        unsigned short vals[8];
#pragma unroll
        for (int j = 0; j < 8; ++j) {
            int ci = cb * 8 + j;
            float s = g0[ci] * rsqrtf(va0[ci] + 1e-5f);
            float t = be0[ci] - me0[ci] * s;
            vals[j] = f2b(in[(size_t)ci * HW + x] * s + t);
        }
        u32x4 pk;
        pk.x = vals[0] | ((unsigned)vals[1] << 16);
        pk.y = vals[2] | ((unsigned)vals[3] << 16);
        pk.z = vals[4] | ((unsigned)vals[5] << 16);
        pk.w = vals[6] | ((unsigned)vals[7] << 16);
        *(u32x4*)(out + (size_t)x * 64 + cb * 8) = pk;
    }
}

// ---------------------------------------------------------------------------
// conv3: 3x3 conv (+residual tap) as implicit GEMM, NHWC padded in/out.
// EPI 0: F = bn1(lrelu(acc + b0sum))   EPI 1: G = lrelu(acc + bconv1)
// grid (2 co-half, 128 y, 6 = map*2+n), block 256 (4 waves, wave = 32 px)
// ---------------------------------------------------------------------------
template <int CIN, int EPI>
__global__ __launch_bounds__(256, 4) void conv3_kernel(
    const unsigned short* I0, const unsigned short* I1, const unsigned short* I2,
    const unsigned short* Wp, const float* bA, const float* bB, const float* bC,
    unsigned short* O0, unsigned short* O1, unsigned short* O2)
{
    constexpr int KCN = CIN / 32;
    constexpr int TKY[10] = {0,0,0,1,1,1,2,2,2,1};
    constexpr int TKX[10] = {0,1,2,0,1,2,0,1,2,1};
    const int tid = threadIdx.x;
    const int lane = tid & 63;
    const int l15 = lane & 15, l4 = lane >> 4;
    const int wv = tid >> 6;
    const int ch = blockIdx.x;
    const int y = blockIdx.y;
    const int mz = blockIdx.z;
    const int map = mz >> 1, n = mz & 1;
    const unsigned short* In = (map == 0 ? I0 : map == 1 ? I1 : I2) + (size_t)n * 130 * 130 * CIN;
    unsigned short* On = (map == 0 ? O0 : map == 1 ? O1 : O2) + (size_t)n * 130 * 130 * 128;

    __shared__ __align__(16) unsigned short stage[3 * 130 * 4 * 8];  // 24,960 B

    f32x4 acc[4][2];
#pragma unroll
    for (int a = 0; a < 4; ++a)
#pragma unroll
        for (int b = 0; b < 2; ++b) acc[a][b] = (f32x4){0.f, 0.f, 0.f, 0.f};

    const int px0 = wv * 32;
    const u32x4* Ap = (const u32x4*)Wp;

    for (int kc = 0; kc < KCN; ++kc) {
        if (kc) __syncthreads();
        // stage 3 rows x 130 x 32ci bf16, source pre-swizzled so ds_read is ~conflict-free
        for (int idx = tid; idx < 1560; idx += 256) {
            int r = idx / 520;
            int rem = idx - r * 520;
            int xx = rem >> 2;
            int slot = rem & 3;
            int cd = slot ^ ((xx >> 1) & 3);
            const unsigned short* src = In + ((size_t)(y + r) * 130 + xx) * CIN + kc * 32 + cd * 8;
            gload16(src, stage + (size_t)(idx & ~63) * 8);
        }
        __syncthreads();
#pragma unroll
        for (int t = 0; t < 10; ++t) {
            const int ky = TKY[t], kx = TKX[t];
            u32x4 a[4];
#pragma unroll
            for (int mi = 0; mi < 4; ++mi)
                a[mi] = Ap[((size_t)(t * KCN + kc) * 8 + ch * 4 + mi) * 64 + lane];
            bf16x8 bv[2];
#pragma unroll
            for (int nf = 0; nf < 2; ++nf) {
                int xx = px0 + nf * 16 + l15 + kx;
                int slot = l4 ^ ((xx >> 1) & 3);
                bv[nf] = *(const bf16x8*)(stage + ((size_t)(ky * 130 + xx) * 4 + slot) * 8);
            }
#pragma unroll
            for (int mi = 0; mi < 4; ++mi) {
                bf16x8 av = __builtin_bit_cast(bf16x8, a[mi]);
#pragma unroll
                for (int nf = 0; nf < 2; ++nf)
                    acc[mi][nf] = __builtin_amdgcn_mfma_f32_16x16x32_bf16(av, bv[nf], acc[mi][nf], 0, 0, 0);
            }
        }
    }
    // epilogue: bias + lrelu (+ BN1 fold for EPI 0), store NHWC bf16 interior
#pragma unroll
    for (int mi = 0; mi < 4; ++mi) {
#pragma unroll
        for (int nf = 0; nf < 2; ++nf) {
            int px = px0 + nf * 16 + l15;
            int cobase = (ch * 4 + mi) * 16 + l4 * 4;
            float t4[4];
#pragma unroll
            for (int r = 0; r < 4; ++r) {
                int co = cobase + r;
                float v = acc[mi][nf][r] + bA[co];
                v = v > 0.f ? v : 0.05f * v;
                if (EPI == 0) v = v * bB[co] + bC[co];
                t4[r] = v;
            }
            unsigned short* op = On + ((size_t)(y + 1) * 130 + (px + 1)) * 128 + cobase;
            *(unsigned*)(op)     = (unsigned)f2b(t4[0]) | ((unsigned)f2b(t4[1]) << 16);
            *(unsigned*)(op + 2) = (unsigned)f2b(t4[2]) | ((unsigned)f2b(t4[3]) << 16);
        }
    }
}

// ---------------------------------------------------------------------------
// proj: 1x1 conv GEMM. z: 0 = G0->KV0 (rows 0..129), 1 = G2->KV2, 2 = G1->Qb
// grid (2 co-half, 130 yy, 6 = proj*2+n), block 256
// ---------------------------------------------------------------------------
__global__ __launch_bounds__(256, 4) void proj_kernel(
    const unsigned short* G0, const unsigned short* G1, const unsigned short* G2,
    const unsigned short* Wqp, const unsigned short* Wkvp,
    const float* bq, const float* bkv,
    unsigned short* KV0, unsigned short* KV2, unsigned short* Qb)
{
    const int z = blockIdx.z;
    const int proj = z >> 1, n = z & 1;
    const int yy = blockIdx.y;
    if (proj == 2 && (yy == 0 || yy == 129)) return;
    const int tid = threadIdx.x;
    const int lane = tid & 63, l15 = lane & 15, l4 = lane >> 4, wv = tid >> 6;
    const int ch = blockIdx.x;
    const unsigned short* In = (proj == 0 ? G0 : proj == 1 ? G2 : G1) + (size_t)n * 130 * 130 * 128;
    const unsigned short* Wp = (proj == 2) ? Wqp : Wkvp;
    const float* bias = (proj == 2) ? bq : bkv;

    __shared__ __align__(16) unsigned short stage[130 * 4 * 8];

    f32x4 acc[4][2];
#pragma unroll
    for (int a = 0; a < 4; ++a)
#pragma unroll
        for (int b = 0; b < 2; ++b) acc[a][b] = (f32x4){0.f, 0.f, 0.f, 0.f};

    const int px0 = wv * 32;
    const u32x4* Ap = (const u32x4*)Wp;

    for (int kc = 0; kc < 4; ++kc) {
        if (kc) __syncthreads();
        for (int idx = tid; idx < 520; idx += 256) {
            int xx = idx >> 2, slot = idx & 3;
            int cd = slot ^ ((xx >> 1) & 3);
            gload16(In + ((size_t)yy * 130 + xx) * 128 + kc * 32 + cd * 8,
                    stage + (size_t)(idx & ~63) * 8);
        }
        __syncthreads();
        u32x4 a[4];
#pragma unroll
        for (int mi = 0; mi < 4; ++mi)
            a[mi] = Ap[((size_t)kc * 8 + ch * 4 + mi) * 64 + lane];
        bf16x8 bv[2];
#pragma unroll
        for (int nf = 0; nf < 2; ++nf) {
            int xx = px0 + nf * 16 + l15 + 1;
            int slot = l4 ^ ((xx >> 1) & 3);
            bv[nf] = *(const bf16x8*)(stage + ((size_t)xx * 4 + slot) * 8);
        }
#pragma unroll
        for (int mi = 0; mi < 4; ++mi) {
            bf16x8 av = __builtin_bit_cast(bf16x8, a[mi]);
#pragma unroll
            for (int nf = 0; nf < 2; ++nf)
                acc[mi][nf] = __builtin_amdgcn_mfma_f32_16x16x32_bf16(av, bv[nf], acc[mi][nf], 0, 0, 0);
        }
        if (kc < 3) __syncthreads();
    }
#pragma unroll
    for (int mi = 0; mi < 4; ++mi) {
#pragma unroll
        for (int nf = 0; nf < 2; ++nf) {
            int px = px0 + nf * 16 + l15;
            int cobase = (ch * 4 + mi) * 16 + l4 * 4;
            float t4[4];
#pragma unroll
            for (int r = 0; r < 4; ++r) t4[r] = acc[mi][nf][r] + bias[cobase + r];
            unsigned short* op;
            if (proj == 2)
                op = Qb + ((size_t)(n * 128 + yy - 1) * 128 + px) * 128 + cobase;
            else
                op = (proj == 0 ? KV0 : KV2) + ((size_t)(n * 130 + yy) * 130 + (px + 1)) * 128 + cobase;
            *(unsigned*)(op)     = (unsigned)f2b(t4[0]) | ((unsigned)f2b(t4[1]) << 16);
            *(unsigned*)(op + 2) = (unsigned)f2b(t4[2]) | ((unsigned)f2b(t4[3]) << 16);
        }
    }
}

// KV border columns (x = 0 / 129) = bias
__global__ __launch_bounds__(256) void kv_border_kernel(
    unsigned short* KV0, unsigned short* KV2, const float* bkv)
{
    int idx = blockIdx.x * 256 + threadIdx.x;
    if (idx >= 16640) return;
    int cb = idx & 15;
    int t = idx >> 4;
    int col = t & 1; t >>= 1;
    int yy = t % 130; t /= 130;
    int n = t & 1;
    int buf = t >> 1;
    unsigned short* p = (buf ? KV2 : KV0)
        + ((size_t)(n * 130 + yy) * 130 + (col ? 129 : 0)) * 128 + cb * 8;
    u16x8 v;
#pragma unroll
    for (int j = 0; j < 8; ++j) v[j] = f2b(bkv[cb * 8 + j]);
    *(u16x8*)p = v;
}

// ---------------------------------------------------------------------------
// attention v3: tile 2y x 32x x 4heads per block (256 threads, 1 px.head each)
// ALL global access via full-line staged LDS:
//   Q tile 2x32 px (16KB), KV window 4x36 px (36.9KB, branches sequential),
//   outputs coalesced through f32 LDS (aliases KV buffer).
// grid 512; XCD-chunked: work = (bid&7)*64 + bid>>3 -> each XCD = 32 y of one n
// ---------------------------------------------------------------------------
__global__ __launch_bounds__(256, 2) void attn_kernel(
    const unsigned short* Qb, const unsigned short* KV0,
    const unsigned short* KV2, float* pass, unsigned short* A1p)
{
    const int bid = blockIdx.x;
    const int work = (bid & 7) * 64 + (bid >> 3);
    const int n   = work >> 8;
    const int rem = work & 255;
    const int yt  = rem >> 2;        // 0..63
    const int xt  = rem & 3;         // 0..3
    const int y0  = yt * 2;
    const int x0  = xt * 32;

    const int tid = threadIdx.x;
    const int h   = tid & 3;
    const int pxl = (tid >> 2) & 31;
    const int py  = tid >> 7;
    const float SC = 0.17677669529663687f;   // 32^-0.5

    __shared__ __align__(16) unsigned char smem[53248];
    unsigned short* kvb = (unsigned short*)smem;            // [4 rows][36 px][128] bf16
    unsigned short* qsb = (unsigned short*)(smem + 36864);  // [2 rows][32 px][128] bf16
    float* outlds = (float*)smem;                           // [64 px][133] f32 (aliases kvb)

    // ---- stage Q (16 wave-groups x 1KB, contiguous, swizzled chunks) ----
#pragma unroll
    for (int it = 0; it < 4; ++it) {
        int idx = it * 256 + tid;
        int g = idx >> 6, l = idx & 63;
        int r = g >> 3, s = g & 7;
        int px = s * 4 + (l >> 4);
        int c  = (l & 15) ^ (px & 7);
        gload16(Qb + (((size_t)(n * 128 + y0 + r) * 128) + x0 + px) * 128 + c * 8,
                qsb + (size_t)g * 512);
    }
    // ---- stage KV branch 0 (36 wave-groups x 1KB) ----
#pragma unroll
    for (int it = 0; it < 9; ++it) {
        int idx = it * 256 + tid;
        int g = idx >> 6, l = idx & 63;
        int r = g / 9, s = g - r * 9;
        int px = s * 4 + (l >> 4);
        int c  = (l & 15) ^ (px & 7);
        gload16(KV0 + (((size_t)(n * 130 + y0 + r) * 130) + x0 + px) * 128 + c * 8,
                kvb + (size_t)g * 512);
    }
    __syncthreads();

    // Q into registers (scale folded)
    float qf[32];
    {
        const unsigned short* qbase = qsb + (size_t)(py * 32 + pxl) * 128;
#pragma unroll
        for (int d8 = 0; d8 < 4; ++d8) {
            int c = ((h << 2) | d8) ^ (pxl & 7);
            u16x8 q8 = *(const u16x8*)(qbase + c * 8);
#pragma unroll
            for (int j = 0; j < 8; ++j) qf[d8 * 8 + j] = b2f(q8[j]) * SC;
        }
    }

    float o[32];
#pragma unroll
    for (int d = 0; d < 32; ++d) o[d] = 0.f;

    for (int b = 0; b < 2; ++b) {
        if (b == 1) {
            __syncthreads();   // everyone done reading kvb from branch 0
#pragma unroll
            for (int it = 0; it < 9; ++it) {
                int idx = it * 256 + tid;
                int g = idx >> 6, l = idx & 63;
                int r = g / 9, s = g - r * 9;
                int px = s * 4 + (l >> 4);
                int c  = (l & 15) ^ (px & 7);
                gload16(KV2 + (((size_t)(n * 130 + y0 + r) * 130) + x0 + px) * 128 + c * 8,
                        kvb + (size_t)g * 512);
            }
            __syncthreads();
        }
        float lg[9];
#pragma unroll
        for (int t = 0; t < 9; ++t) {
            int ky = t / 3, kx = t % 3;
            int pxw = pxl + kx;
            const unsigned short* base = kvb + ((size_t)(py + ky) * 36 + pxw) * 128;
            float s = 0.f;
#pragma unroll
            for (int d8 = 0; d8 < 4; ++d8) {
                int c = ((h << 2) | d8) ^ (pxw & 7);
                u16x8 kk = *(const u16x8*)(base + c * 8);
#pragma unroll
                for (int j = 0; j < 8; ++j) s += qf[d8 * 8 + j] * b2f(kk[j]);
            }
            lg[t] = s;
        }
        float mv = lg[0];
#pragma unroll
        for (int t = 1; t < 9; ++t) mv = fmaxf(mv, lg[t]);
        float w[9], sum = 0.f;
#pragma unroll
        for (int t = 0; t < 9; ++t) { w[t] = __expf(lg[t] - mv); sum += w[t]; }
        float r = 0.5f / sum;
#pragma unroll
        for (int t = 0; t < 9; ++t) w[t] *= r;
#pragma unroll
        for (int t = 0; t < 9; ++t) {
            int ky = t / 3, kx = t % 3;
            int pxw = pxl + kx;
            const unsigned short* base = kvb + ((size_t)(py + ky) * 36 + pxw) * 128;
#pragma unroll
            for (int d8 = 0; d8 < 4; ++d8) {
                int c = ((h << 2) | d8) ^ (pxw & 7);
                u16x8 kk = *(const u16x8*)(base + c * 8);
#pragma unroll
                for (int j = 0; j < 8; ++j) o[d8 * 8 + j] += w[t] * b2f(kk[j]);
            }
        }
    }

    __syncthreads();   // done reading kvb (outlds aliases it)

    // stage outputs: outlds[px_lin][h*33 + d]  (33 stride -> h-lanes conflict-free)
    {
        float* orow = outlds + (size_t)(py * 32 + pxl) * 133 + h * 33;
#pragma unroll
        for (int d = 0; d < 32; ++d) orow[d] = o[d];
    }
    __syncthreads();

    // pass: f32 NCHW, full 128B lines (16-lane group = 2 rows x 128B)
    {
        const int lane = tid & 63, wvv = tid >> 6;
        const int xs = (lane & 15) * 4;     // px_lin quad base
        const int pyq = xs >> 5, xq = xs & 31;
#pragma unroll
        for (int it = 0; it < 8; ++it) {
            int cc = wvv * 32 + it * 4 + (lane >> 4);
            int col = (cc >> 5) * 33 + (cc & 31);
            f32x4 v = { outlds[(size_t)(xs + 0) * 133 + col],
                        outlds[(size_t)(xs + 1) * 133 + col],
                        outlds[(size_t)(xs + 2) * 133 + col],
                        outlds[(size_t)(xs + 3) * 133 + col] };
            *(f32x4*)(pass + ((size_t)(n * 128 + cc) * HW) + (y0 + pyq) * 128 + x0 + xq) = v;
        }
    }

    // A1p: bf16 NHWC padded, 1KB contiguous per wave instruction
#pragma unroll
    for (int it = 0; it < 4; ++it) {
        int chunk = it * 256 + tid;          // 0..1023
        int pl = chunk >> 4, c16 = chunk & 15;
        int col = (c16 >> 2) * 33 + (c16 & 3) * 8;
        const float* src = outlds + (size_t)pl * 133 + col;
        u16x8 v;
#pragma unroll
        for (int j = 0; j < 8; ++j) v[j] = f2b(src[j]);
        *(u16x8*)(A1p + ((size_t)(n * 130 + y0 + (pl >> 5) + 1) * 130 + (x0 + (pl & 31) + 1)) * 128 + c16 * 8) = v;
    }
}

// ---------------------------------------------------------------------------
// pool: 3x3 stride-2 conv, NHWC padded bf16 in -> f32 NCHW out (2,128,64,64)
// grid (2 co-half, 64 yo, 6 = map*2+n), block 256 (4 waves, 16 px each)
// ---------------------------------------------------------------------------
__global__ __launch_bounds__(256, 4) void pool_kernel(
    const unsigned short* G0, const unsigned short* A1, const unsigned short* G2,
    const unsigned short* Wpp, const float* bp, float* out)
{
    const int z = blockIdx.z;
    const int map = z >> 1, n = z & 1;
    const int yo = blockIdx.y;
    const int ch = blockIdx.x;
    const int tid = threadIdx.x, lane = tid & 63, l15 = lane & 15, l4 = lane >> 4, wv = tid >> 6;
    const unsigned short* In = (map == 0 ? G0 : map == 1 ? A1 : G2) + (size_t)n * 130 * 130 * 128;
    float* outp = out + (size_t)map * 1048576 + (size_t)n * 524288;

    __shared__ __align__(16) unsigned short stage[3 * 130 * 4 * 8];

    f32x4 acc[4];
#pragma unroll
    for (int a = 0; a < 4; ++a) acc[a] = (f32x4){0.f, 0.f, 0.f, 0.f};

    const int px0 = wv * 16;
    const u32x4* Ap = (const u32x4*)Wpp;

    for (int kc = 0; kc < 4; ++kc) {
        if (kc) __syncthreads();
        for (int idx = tid; idx < 1560; idx += 256) {
            int r = idx / 520;
            int rem = idx - r * 520;
            int xx = rem >> 2;
            int slot = rem & 3;
            int cd = slot ^ ((xx >> 1) & 3);
            gload16(In + ((size_t)(2 * yo + r) * 130 + xx) * 128 + kc * 32 + cd * 8,
                    stage + (size_t)(idx & ~63) * 8);
        }
        __syncthreads();
#pragma unroll
        for (int t = 0; t < 9; ++t) {
            const int ky = t / 3, kx = t % 3;
            u32x4 a[4];
#pragma unroll
            for (int mi = 0; mi < 4; ++mi)
                a[mi] = Ap[((size_t)(t * 4 + kc) * 8 + ch * 4 + mi) * 64 + lane];
            int xx = 2 * (px0 + l15) + kx;
            int slot = l4 ^ ((xx >> 1) & 3);
            bf16x8 bv = *(const bf16x8*)(stage + ((size_t)(ky * 130 + xx) * 4 + slot) * 8);
#pragma unroll
            for (int mi = 0; mi < 4; ++mi)
                acc[mi] = __builtin_amdgcn_mfma_f32_16x16x32_bf16(
                    __builtin_bit_cast(bf16x8, a[mi]), bv, acc[mi], 0, 0, 0);
        }
    }
#pragma unroll
    for (int mi = 0; mi < 4; ++mi) {
        int cobase = (ch * 4 + mi) * 16 + l4 * 4;
        int px = px0 + l15;
#pragma unroll
        for (int r = 0; r < 4; ++r) {
            int co = cobase + r;
            outp[((size_t)co * 64 + yo) * 64 + px] = acc[mi][r] + bp[co];
        }
    }
}

// ---------------------------------------------------------------------------
extern "C" void kernel_launch(void* const* d_in, const int* in_sizes, int n_in,
                              void* d_out, int out_size, void* d_ws, size_t ws_size,
                              hipStream_t stream)
{
    const float* x0 = (const float*)d_in[0];
    const float* x1 = (const float*)d_in[1];
    const float* x2 = (const float*)d_in[2];
    const float* gamma0 = (const float*)d_in[3];
    const float* beta0  = (const float*)d_in[4];
    const float* mean0  = (const float*)d_in[5];
    const float* var0   = (const float*)d_in[6];
    const float* gamma1 = (const float*)d_in[7];
    const float* beta1  = (const float*)d_in[8];
    const float* mean1  = (const float*)d_in[9];
    const float* var1   = (const float*)d_in[10];
    const float* W_adj  = (const float*)d_in[11];
    const float* b_adj  = (const float*)d_in[12];
    const float* W_conv0 = (const float*)d_in[13];
    const float* b_conv0 = (const float*)d_in[14];
    const float* W_conv1 = (const float*)d_in[15];
    const float* b_conv1 = (const float*)d_in[16];
    const float* Wq  = (const float*)d_in[17];
    const float* bq  = (const float*)d_in[18];
    const float* Wkv = (const float*)d_in[19];
    const float* bkv = (const float*)d_in[20];
    const float* W_pool = (const float*)d_in[21];
    const float* b_pool = (const float*)d_in[22];

    float* out  = (float*)d_out;
    float* pass = out + 3145728;                 // (2,128,128,128) f32 NCHW

    char* wsb = (char*)d_ws;
    const size_t FSZ = 8652800;                  // 2*130*130*128*2 B
    const size_t XSZ = 4326400;                  // 2*130*130*64*2 B
    unsigned short* F0 = (unsigned short*)(wsb);
    unsigned short* F1 = (unsigned short*)(wsb + FSZ);
    unsigned short* F2 = (unsigned short*)(wsb + 2 * FSZ);
    unsigned short* G0 = (unsigned short*)(wsb + 3 * FSZ);
    unsigned short* G1 = (unsigned short*)(wsb + 4 * FSZ);
    unsigned short* G2 = (unsigned short*)(wsb + 5 * FSZ);
    unsigned short* X0 = (unsigned short*)(wsb + 6 * FSZ);
    unsigned short* X1 = (unsigned short*)(wsb + 6 * FSZ + XSZ);
    unsigned short* X2 = (unsigned short*)(wsb + 6 * FSZ + 2 * XSZ);
    char* WAR = wsb + 6 * FSZ + 3 * XSZ;
    unsigned short* W0p    = (unsigned short*)(WAR);
    unsigned short* W1p    = (unsigned short*)(WAR + 163840);
    unsigned short* Wqp    = (unsigned short*)(WAR + 491520);
    unsigned short* Wkvp   = (unsigned short*)(WAR + 524288);
    unsigned short* Wpoolp = (unsigned short*)(WAR + 557056);
    float* b0sum = (float*)(WAR + 851968);
    float* s1a   = (float*)(WAR + 852480);
    float* t1a   = (float*)(WAR + 852992);
    // aliases (lifetimes disjoint, stream-ordered)
    unsigned short* KV0 = F0;
    unsigned short* KV2 = F1;
    unsigned short* Qb  = F2;
    unsigned short* A1p = X0;   // spans X0+X1

    zero_borders_kernel<<<dim3(65, 1, 9), 256, 0, stream>>>(X0, X1, X2, F0, F1, F2, G0, G1, G2);
    pack_kernel<<<dim3(80, 1, 6), 256, 0, stream>>>(
        W_conv0, W_adj, W_conv1, Wq, Wkv, W_pool, b_conv0, b_adj,
        gamma1, beta1, mean1, var1, W0p, W1p, Wqp, Wkvp, Wpoolp, b0sum, s1a, t1a);
    prep_kernel<<<dim3(128, 6), 256, 0, stream>>>(
        x0, x1, x2, gamma0, beta0, mean0, var0, X0, X1, X2);

    conv3_kernel<64, 0><<<dim3(2, 128, 6), 256, 0, stream>>>(
        X0, X1, X2, W0p, b0sum, s1a, t1a, F0, F1, F2);
    conv3_kernel<128, 1><<<dim3(2, 128, 6), 256, 0, stream>>>(
        F0, F1, F2, W1p, b_conv1, nullptr, nullptr, G0, G1, G2);

    zero_one_kernel<<<dim3(65), 256, 0, stream>>>(A1p);
    proj_kernel<<<dim3(2, 130, 6), 256, 0, stream>>>(
        G0, G1, G2, Wqp, Wkvp, bq, bkv, KV0, KV2, Qb);
    kv_border_kernel<<<dim3(65), 256, 0, stream>>>(KV0, KV2, bkv);

    attn_kernel<<<dim3(512), 256, 0, stream>>>(Qb, KV0, KV2, pass, A1p);

    pool_kernel<<<dim3(2, 64, 6), 256, 0, stream>>>(G0, A1p, G2, Wpoolp, b_pool, out);
}